// Round 1
// baseline (255.586 us; speedup 1.0000x reference)
//
#include <hip/hip_runtime.h>
#include <math.h>
#include <stdint.h>

#define D_MODEL 1024
#define N_HEADS 16
#define HEAD_DIM 64
#define BATCH 2
#define SEQ 2048
#define TOKENS (BATCH * SEQ)   // 4096

typedef __attribute__((ext_vector_type(8))) short short8;   // 8 bf16 = 4 VGPRs
typedef __attribute__((ext_vector_type(4))) float floatx4;  // MFMA C/D frag

#define BMFMA(a, b, c) __builtin_amdgcn_mfma_f32_16x16x32_bf16(a, b, c, 0, 0, 0)

__device__ __forceinline__ unsigned short f2bf(float f) {
    uint32_t u = __float_as_uint(f);
    u += 0x7fffu + ((u >> 16) & 1u);
    return (unsigned short)(u >> 16);
}
__device__ __forceinline__ float bf2f(unsigned short h) {
    return __uint_as_float(((uint32_t)h) << 16);
}

// async global -> LDS, 16B per lane; LDS dest = wave-uniform base + lane*16
#define GLD_LDS16(gp, lp) __builtin_amdgcn_global_load_lds(                 \
    (const __attribute__((address_space(1))) void*)(gp),                    \
    (__attribute__((address_space(3))) void*)(lp), 16, 0, 0)

// ---------------------------------------------------------------------------
// Merged input prep:
//   blocks [0,4096)      : x -> Ax (bf16 hi|lo)
//   blocks [4096,7168)   : W_qkv -> Bt (transpose + hi|lo split)
//   blocks [7168,8192)   : W_out -> Bt2 (transpose + hi|lo split; was split_w_t)
//   block  8192          : attention_mask -> 64-bit per-k-tile bitmask
// ---------------------------------------------------------------------------
__global__ __launch_bounds__(256) void split_inputs(
    const float* __restrict__ X, const float* __restrict__ Wqkv,
    const float* __restrict__ Wout, const int* __restrict__ am,
    unsigned short* __restrict__ Ax, unsigned short* __restrict__ Bt,
    unsigned short* __restrict__ Bt2, unsigned long long* __restrict__ mbits)
{
    __shared__ float t[32][33];
    const int tid = threadIdx.x;
    const int bid = blockIdx.x;
    if (bid < 4096) {
        const int idx = bid * 256 + tid;
        const int row = idx >> 8;
        const int c = (idx & 255) * 4;
        float4 v = *(const float4*)(X + (size_t)row * 1024 + c);
        float f[4] = {v.x, v.y, v.z, v.w};
        uint32_t hp[2], lp[2];
#pragma unroll
        for (int j = 0; j < 2; ++j) {
            unsigned short h0 = f2bf(f[2 * j]), h1 = f2bf(f[2 * j + 1]);
            hp[j] = (uint32_t)h0 | ((uint32_t)h1 << 16);
            lp[j] = (uint32_t)f2bf(f[2 * j] - bf2f(h0)) |
                    ((uint32_t)f2bf(f[2 * j + 1] - bf2f(h1)) << 16);
        }
        *(uint2*)(Ax + (size_t)row * 2048 + c) = make_uint2(hp[0], hp[1]);
        *(uint2*)(Ax + (size_t)row * 2048 + 1024 + c) = make_uint2(lp[0], lp[1]);
    } else if (bid < 7168) {
        const int id = bid - 4096;                 // 0..3071
        const int n0 = (id % 96) * 32, k0 = (id / 96) * 32;
        const int c = tid & 31, r = tid >> 5;
#pragma unroll
        for (int i = 0; i < 4; ++i)
            t[r + 8 * i][c] = Wqkv[(size_t)(k0 + r + 8 * i) * 3072 + n0 + c];
        __syncthreads();
#pragma unroll
        for (int i = 0; i < 4; ++i) {
            int dn = r + 8 * i;
            float f = t[c][dn];
            unsigned short hi = f2bf(f);
            unsigned short lo = f2bf(f - bf2f(hi));
            size_t row = (size_t)(n0 + dn) * 2048;
            Bt[row + k0 + c] = hi;
            Bt[row + 1024 + k0 + c] = lo;
        }
    } else if (bid < 8192) {
        const int id = bid - 7168;                 // 0..1023: W_out 32x32 tiles
        const int n0 = (id & 31) * 32, k0 = (id >> 5) * 32;
        const int c = tid & 31, r = tid >> 5;
#pragma unroll
        for (int i = 0; i < 4; ++i)
            t[r + 8 * i][c] = Wout[(size_t)(k0 + r + 8 * i) * 1024 + n0 + c];
        __syncthreads();
#pragma unroll
        for (int i = 0; i < 4; ++i) {
            int dn = r + 8 * i;
            float f = t[c][dn];
            unsigned short hi = f2bf(f);
            unsigned short lo = f2bf(f - bf2f(hi));
            size_t row = (size_t)(n0 + dn) * 2048;
            Bt2[row + k0 + c] = hi;
            Bt2[row + 1024 + k0 + c] = lo;
        }
    } else {
        // mask bitmap: one uint64 per 64-token tile (B*SEQ/64 = 64 tiles)
        if (tid < 64) {
            const int* a = am + tid * 64;
            unsigned long long m = 0ull;
            for (int j = 0; j < 64; ++j)
                m |= (unsigned long long)(a[j] != 0 ? 1u : 0u) << j;
            mbits[tid] = m;
        }
    }
}

// ---------------------------------------------------------------------------
// FUSED x3 bf16 MFMA GEMM (R6 structure), 1D grid + 8-wide M-supertile
// swizzle. A: Ax [M][2048] hi|lo. B: Bt rows [n][2048] hi|lo. C stride ldc.
// ---------------------------------------------------------------------------
template<int WM, int WN, int FM, int FN>
__global__ __launch_bounds__(256) void gemm_mfma_x3f(
    const unsigned short* __restrict__ Ax, const unsigned short* __restrict__ Bt,
    const float* __restrict__ bias, float* __restrict__ C, int ldc, int nTiles)
{
    constexpr int BM = WM * FM * 16;
    constexpr int BN = WN * FN * 16;
    constexpr int NA = BM / 64;
    constexpr int NB = BN / 64;

    __shared__ __align__(16) unsigned short sAh[BM * 32];
    __shared__ __align__(16) unsigned short sAl[BM * 32];
    __shared__ __align__(16) unsigned short sBh[BN * 32];
    __shared__ __align__(16) unsigned short sBl[BN * 32];

    const int tid = threadIdx.x;
    const int w = tid >> 6, lane = tid & 63;
    const int l15 = lane & 15, quad = lane >> 4;
    const int wm = w / WN, wn = w % WN;

    const int lin = blockIdx.x;
    const int msuper = lin / (8 * nTiles);
    const int rem = lin % (8 * nTiles);
    const int m0 = (msuper * 8 + (rem & 7)) * BM;
    const int n0 = (rem >> 3) * BN;

    const int ch = (lane & 3) ^ ((lane >> 3) & 3);       // staging swizzle
    const int sw = (quad ^ ((l15 >> 1) & 3)) * 8;        // frag-read swizzle

    const unsigned short* aG[NA];
    const unsigned short* bG[NB];
#pragma unroll
    for (int i = 0; i < NA; ++i)
        aG[i] = Ax + (size_t)(m0 + (w * NA + i) * 16 + (lane >> 2)) * 2048
                   + ch * 8;
#pragma unroll
    for (int i = 0; i < NB; ++i)
        bG[i] = Bt + (size_t)(n0 + (w * NB + i) * 16 + (lane >> 2)) * 2048
                   + ch * 8;

    floatx4 acc[FM][FN];
#pragma unroll
    for (int fm = 0; fm < FM; ++fm)
#pragma unroll
        for (int fn = 0; fn < FN; ++fn) acc[fm][fn] = (floatx4)0.f;

    for (int ks = 0; ks < 32; ++ks) {
        const int ko = ks * 32;          // hi at ko, lo at 1024+ko
        __syncthreads();
#pragma unroll
        for (int i = 0; i < NA; ++i) {
            GLD_LDS16(aG[i] + ko,        sAh + (w * NA + i) * 512);
            GLD_LDS16(aG[i] + 1024 + ko, sAl + (w * NA + i) * 512);
        }
#pragma unroll
        for (int i = 0; i < NB; ++i) {
            GLD_LDS16(bG[i] + ko,        sBh + (w * NB + i) * 512);
            GLD_LDS16(bG[i] + 1024 + ko, sBl + (w * NB + i) * 512);
        }
        __syncthreads();

        short8 ah[FM], al[FM], bh[FN], bl[FN];
#pragma unroll
        for (int fm = 0; fm < FM; ++fm) {
            const int off = ((wm * FM + fm) * 16 + l15) * 32 + sw;
            ah[fm] = *(const short8*)&sAh[off];
            al[fm] = *(const short8*)&sAl[off];
        }
#pragma unroll
        for (int fn = 0; fn < FN; ++fn) {
            const int off = ((wn * FN + fn) * 16 + l15) * 32 + sw;
            bh[fn] = *(const short8*)&sBh[off];
            bl[fn] = *(const short8*)&sBl[off];
        }
#pragma unroll
        for (int fm = 0; fm < FM; ++fm)
#pragma unroll
            for (int fn = 0; fn < FN; ++fn) {
                floatx4 a = acc[fm][fn];
                a = BMFMA(ah[fm], bh[fn], a);
                a = BMFMA(ah[fm], bl[fn], a);
                a = BMFMA(al[fm], bh[fn], a);
                acc[fm][fn] = a;
            }
    }

#pragma unroll
    for (int fm = 0; fm < FM; ++fm)
#pragma unroll
        for (int fn = 0; fn < FN; ++fn) {
            int col = n0 + (wn * FN + fn) * 16 + l15;
            float bv = bias[col];
#pragma unroll
            for (int r = 0; r < 4; ++r) {
                int row = m0 + (wm * FM + fm) * 16 + quad * 4 + r;
                C[(size_t)row * ldc + col] = acc[fm][fn][r] + bv;
            }
        }
}

// ---------------------------------------------------------------------------
// Single-precision bf16 MFMA GEMM. BK=64, runtime A/B/C strides.
// Used for: V-columns of the QKV projection and the out-projection.
// ---------------------------------------------------------------------------
template<int WM, int WN, int FM, int FN>
__global__ __launch_bounds__(256) void gemm_mfma_s(
    const unsigned short* __restrict__ A, int lda,
    const unsigned short* __restrict__ Bt, int ldb,
    const float* __restrict__ bias, float* __restrict__ C, int ldc, int nTiles)
{
    constexpr int BM = WM * FM * 16;
    constexpr int BN = WN * FN * 16;
    constexpr int NA = BM / 64;
    constexpr int NB = BN / 64;

    __shared__ __align__(16) unsigned short sA0[BM * 32];
    __shared__ __align__(16) unsigned short sA1[BM * 32];
    __shared__ __align__(16) unsigned short sB0[BN * 32];
    __shared__ __align__(16) unsigned short sB1[BN * 32];

    const int tid = threadIdx.x;
    const int w = tid >> 6, lane = tid & 63;
    const int l15 = lane & 15, quad = lane >> 4;
    const int wm = w / WN, wn = w % WN;

    const int lin = blockIdx.x;
    const int msuper = lin / (8 * nTiles);
    const int rem = lin % (8 * nTiles);
    const int m0 = (msuper * 8 + (rem & 7)) * BM;
    const int n0 = (rem >> 3) * BN;

    const int ch = (lane & 3) ^ ((lane >> 3) & 3);
    const int sw = (quad ^ ((l15 >> 1) & 3)) * 8;

    const unsigned short* aG[NA];
    const unsigned short* bG[NB];
#pragma unroll
    for (int i = 0; i < NA; ++i)
        aG[i] = A + (size_t)(m0 + (w * NA + i) * 16 + (lane >> 2)) * lda + ch * 8;
#pragma unroll
    for (int i = 0; i < NB; ++i)
        bG[i] = Bt + (size_t)(n0 + (w * NB + i) * 16 + (lane >> 2)) * ldb + ch * 8;

    floatx4 acc[FM][FN];
#pragma unroll
    for (int fm = 0; fm < FM; ++fm)
#pragma unroll
        for (int fn = 0; fn < FN; ++fn) acc[fm][fn] = (floatx4)0.f;

    for (int ks = 0; ks < 16; ++ks) {
        const int ko = ks * 64;
        __syncthreads();
#pragma unroll
        for (int i = 0; i < NA; ++i) {
            GLD_LDS16(aG[i] + ko,      sA0 + (w * NA + i) * 512);
            GLD_LDS16(aG[i] + ko + 32, sA1 + (w * NA + i) * 512);
        }
#pragma unroll
        for (int i = 0; i < NB; ++i) {
            GLD_LDS16(bG[i] + ko,      sB0 + (w * NB + i) * 512);
            GLD_LDS16(bG[i] + ko + 32, sB1 + (w * NB + i) * 512);
        }
        __syncthreads();

        short8 a0[FM], a1[FM], b0[FN], b1[FN];
#pragma unroll
        for (int fm = 0; fm < FM; ++fm) {
            const int off = ((wm * FM + fm) * 16 + l15) * 32 + sw;
            a0[fm] = *(const short8*)&sA0[off];
            a1[fm] = *(const short8*)&sA1[off];
        }
#pragma unroll
        for (int fn = 0; fn < FN; ++fn) {
            const int off = ((wn * FN + fn) * 16 + l15) * 32 + sw;
            b0[fn] = *(const short8*)&sB0[off];
            b1[fn] = *(const short8*)&sB1[off];
        }
#pragma unroll
        for (int fm = 0; fm < FM; ++fm)
#pragma unroll
            for (int fn = 0; fn < FN; ++fn) {
                floatx4 a = acc[fm][fn];
                a = BMFMA(a0[fm], b0[fn], a);
                a = BMFMA(a1[fm], b1[fn], a);
                acc[fm][fn] = a;
            }
    }

#pragma unroll
    for (int fm = 0; fm < FM; ++fm)
#pragma unroll
        for (int fn = 0; fn < FN; ++fn) {
            int col = n0 + (wn * FN + fn) * 16 + l15;
            float bv = bias[col];
#pragma unroll
            for (int r = 0; r < 4; ++r) {
                int row = m0 + (wm * FM + fm) * 16 + quad * 4 + r;
                C[(size_t)row * ldc + col] = acc[fm][fn][r] + bv;
            }
        }
}

// ---------------------------------------------------------------------------
// prep_qkv: RoPE + 1/8 q-scale + bf16 split. Q hi / K hi+lo [bh][t][64];
// V hi [bh][d][2048] transposed.
// ---------------------------------------------------------------------------
__global__ __launch_bounds__(256) void prep_qkv(
    const float* __restrict__ qkv,
    unsigned short* __restrict__ Qh,
    unsigned short* __restrict__ Kh, unsigned short* __restrict__ Kl,
    unsigned short* __restrict__ Vh)
{
    __shared__ float vt[64][65];
    const int tid = threadIdx.x;
    const int lin = blockIdx.x;
    const int tt = lin & 31, bh = lin >> 5;
    const int b = bh >> 4, h = bh & 15;
    const int r = tid >> 2;
    const int dblk = (tid & 3) * 16;
    const int tg = tt * 64 + r;
    const size_t src = (size_t)(b * SEQ + tg) * 3072 + h * 64 + dblk;
    const size_t dst = ((size_t)bh * SEQ + tg) * 64 + dblk;

    float q[16], k[16], v[16];
#pragma unroll
    for (int i = 0; i < 4; ++i) {
        *(float4*)&q[4 * i] = *(const float4*)(qkv + src + 4 * i);
        *(float4*)&k[4 * i] = *(const float4*)(qkv + src + 1024 + 4 * i);
        *(float4*)&v[4 * i] = *(const float4*)(qkv + src + 2048 + 4 * i);
    }
#pragma unroll
    for (int j = 0; j < 16; j += 2) {
        int pr = (dblk + j) >> 1;
        double e = (double)(2 * pr) / 64.0;
        float inv = (float)exp2(-e * 13.287712379549449);
        float ang = (float)tg * inv;
        float s, c;
        __sincosf(ang, &s, &c);
        float qe = q[j], qo = q[j + 1];
        q[j] = qe * c - qo * s; q[j + 1] = qe * s + qo * c;
        float ke = k[j], ko = k[j + 1];
        k[j] = ke * c - ko * s; k[j + 1] = ke * s + ko * c;
    }
    uint32_t ph[8], pl[8];
#pragma unroll
    for (int j = 0; j < 8; ++j) {
        float f0 = q[2 * j] * 0.125f, f1 = q[2 * j + 1] * 0.125f;
        ph[j] = (uint32_t)f2bf(f0) | ((uint32_t)f2bf(f1) << 16);
    }
    *(uint4*)(Qh + dst) = *(uint4*)&ph[0]; *(uint4*)(Qh + dst + 8) = *(uint4*)&ph[4];
#pragma unroll
    for (int j = 0; j < 8; ++j) {
        float f0 = k[2 * j], f1 = k[2 * j + 1];
        unsigned short h0 = f2bf(f0), h1 = f2bf(f1);
        ph[j] = (uint32_t)h0 | ((uint32_t)h1 << 16);
        pl[j] = (uint32_t)f2bf(f0 - bf2f(h0)) | ((uint32_t)f2bf(f1 - bf2f(h1)) << 16);
    }
    *(uint4*)(Kh + dst) = *(uint4*)&ph[0]; *(uint4*)(Kh + dst + 8) = *(uint4*)&ph[4];
    *(uint4*)(Kl + dst) = *(uint4*)&pl[0]; *(uint4*)(Kl + dst + 8) = *(uint4*)&pl[4];

#pragma unroll
    for (int j = 0; j < 16; ++j) vt[r][dblk + j] = v[j];
    __syncthreads();
    const int d2 = tid >> 2;
    const int tb = (tid & 3) * 16;
#pragma unroll
    for (int j = 0; j < 8; ++j) {
        float f0 = vt[tb + 2 * j][d2], f1 = vt[tb + 2 * j + 1][d2];
        ph[j] = (uint32_t)f2bf(f0) | ((uint32_t)f2bf(f1) << 16);
    }
    const size_t vdst = ((size_t)bh * 64 + d2) * SEQ + tt * 64 + tb;
    *(uint4*)(Vh + vdst) = *(uint4*)&ph[0]; *(uint4*)(Vh + vdst + 8) = *(uint4*)&ph[4];
}

// ---------------------------------------------------------------------------
// MFMA flash attention, R11:
//  - paired q-tiles: block handles qt=31-p then qt=p  -> uniform 33 iters,
//    512 blocks, zero tail (was: 1024 blocks, makespan = 32-iter critical path)
//  - double-buffered K/V staging: prefetch kt+1 before compute(kt); the
//    barrier's vmcnt(0) drain is then free (loads flew under compute)
//  - mask as 64-bit-per-tile bitmap held in lane registers, broadcast by
//    __shfl -> zero VMEM on the compute path (was 4x int4 global loads/iter)
//  - XCD swizzle: 64 consecutive blocks (4 bh = 3MB K/V) per XCD L2
// LDS 56KB -> 2 blocks/CU resident.
// ---------------------------------------------------------------------------
__global__ __launch_bounds__(256, 4) void flash_mfma(
    const unsigned short* __restrict__ Qh,
    const unsigned short* __restrict__ Kh, const unsigned short* __restrict__ Kl,
    const unsigned short* __restrict__ Vh,
    const unsigned long long* __restrict__ mbits,
    unsigned short* __restrict__ attnx)
{
    __shared__ __align__(16) unsigned short sKh[2][4096];
    __shared__ __align__(16) unsigned short sKl[2][4096];
    __shared__ __align__(16) unsigned short sVh[2][4096];
    __shared__ __align__(16) unsigned short sP[4096];

    const int tid = threadIdx.x;
    const int lane = tid & 63, w = tid >> 6;
    const int l15 = lane & 15, quad = lane >> 4;
    const int lin0 = blockIdx.x;
    const int lin = (lin0 & 7) * 64 + (lin0 >> 3);   // XCD swizzle, 512 = 8*64
    const int bh = lin >> 4;
    const int p = lin & 15;
    const int b = bh >> 4, h = bh & 15;
    const int sw = (quad ^ ((l15 >> 1) & 3)) * 8;
    const int ch = (lane & 3) ^ ((lane >> 3) & 3);
    unsigned short* pbase = sP + w * 1024;

    short8 ones;
#pragma unroll
    for (int j = 0; j < 8; ++j) ones[j] = (short)0x3F80;  // bf16 1.0

    const int qtA = 31 - p, qtB = p;                      // heavy seg first
    const size_t qbA = ((size_t)bh * SEQ + qtA * 64 + w * 16 + l15) * 64 + quad * 8;
    const size_t qbB = ((size_t)bh * SEQ + qtB * 64 + w * 16 + l15) * 64 + quad * 8;
    const short8 qA0 = *(const short8*)(Qh + qbA);
    const short8 qA1 = *(const short8*)(Qh + qbA + 32);
    const short8 qB0 = *(const short8*)(Qh + qbB);
    const short8 qB1 = *(const short8*)(Qh + qbB + 32);

    // lane l (<32) holds the mask word of k-tile l for this batch
    unsigned int mlo = 0xffffffffu, mhi = 0xffffffffu;
    if (lane < 32) {
        unsigned long long mw = mbits[b * 32 + lane];
        mlo = (unsigned int)mw;
        mhi = (unsigned int)(mw >> 32);
    }

    const size_t kRow0 = ((size_t)bh * SEQ + w * 16 + (lane >> 2)) * 64 + ch * 8;
    const size_t vRow  = ((size_t)bh * 64 + w * 16 + (lane >> 2)) * SEQ + ch * 8;

    auto STAGE = [&](int kt, int sel) {
        const size_t kg = kRow0 + (size_t)kt * 4096;
        const size_t vg = vRow + (size_t)kt * 64;
        GLD_LDS16(Kh + kg,      &sKh[sel][w * 512]);
        GLD_LDS16(Kh + kg + 32, &sKh[sel][2048 + w * 512]);
        GLD_LDS16(Kl + kg,      &sKl[sel][w * 512]);
        GLD_LDS16(Kl + kg + 32, &sKl[sel][2048 + w * 512]);
        GLD_LDS16(Vh + vg,      &sVh[sel][w * 512]);
        GLD_LDS16(Vh + vg + 32, &sVh[sel][2048 + w * 512]);
    };

    int cur = 0;
    STAGE(0, 0);                                   // seg0 kt=0

#pragma unroll
    for (int seg = 0; seg < 2; ++seg) {
        const int qt = seg ? qtB : qtA;
        const short8 q0 = seg ? qB0 : qA0;
        const short8 q1 = seg ? qB1 : qA1;
        const int mg = qt * 64 + w * 16 + l15;

        floatx4 O[4];
        floatx4 lAcc = (floatx4)0.f;
#pragma unroll
        for (int nf = 0; nf < 4; ++nf) O[nf] = (floatx4)0.f;

        for (int kt = 0; kt <= qt; ++kt) {
            __syncthreads();                       // drains stage of tile kt
            if (kt < qt)        STAGE(kt + 1, cur ^ 1);
            else if (seg == 0)  STAGE(0, cur ^ 1); // prefetch seg1 kt=0

            const bool diag = (kt == qt);
            const unsigned int wlo = (unsigned int)__shfl((int)mlo, kt);
            const unsigned int whi = (unsigned int)__shfl((int)mhi, kt);

            // ---- S^T = K Q^T (x2), exp, pack, stage P (wave-private) ----
#pragma unroll
            for (int nf = 0; nf < 4; ++nf) {
                const int base = (nf * 16 + l15) * 32 + sw;
                const short8 kh0 = *(const short8*)&sKh[cur][base];
                const short8 kh1 = *(const short8*)&sKh[cur][2048 + base];
                const short8 kl0 = *(const short8*)&sKl[cur][base];
                const short8 kl1 = *(const short8*)&sKl[cur][2048 + base];
                floatx4 s = (floatx4)0.f;
                s = BMFMA(kh0, q0, s);
                s = BMFMA(kh1, q1, s);
                s = BMFMA(kl0, q0, s);
                s = BMFMA(kl1, q1, s);

                const int tb = kt * 64 + nf * 16 + quad * 4;
                const unsigned int msel = (nf & 2) ? whi : wlo;
                const int p4 = (nf & 1) * 16 + quad * 4;
                float pv[4];
#pragma unroll
                for (int r = 0; r < 4; ++r) {
                    bool ok = ((msel >> (p4 + r)) & 1u) != 0u;
                    if (diag) ok = ok && (tb + r <= mg);
                    pv[r] = ok ? __expf(s[r] - 16.0f) : 0.0f;
                }
                ushort4 pk;
                pk.x = f2bf(pv[0]); pk.y = f2bf(pv[1]);
                pk.z = f2bf(pv[2]); pk.w = f2bf(pv[3]);
                const int pos = (((nf & 1) * 2 + (quad >> 1)) ^ ((l15 >> 1) & 3));
                *(ushort4*)(pbase + (nf >> 1) * 512 + l15 * 32 + pos * 8
                            + (quad & 1) * 4) = pk;
            }

            const short8 pf0 = *(const short8*)(pbase + l15 * 32 + sw);
            const short8 pf1 = *(const short8*)(pbase + 512 + l15 * 32 + sw);

            // ---- l += P @ ones ; O += P @ Vh ----
            lAcc = BMFMA(pf0, ones, lAcc);
            lAcc = BMFMA(pf1, ones, lAcc);
#pragma unroll
            for (int nf = 0; nf < 4; ++nf) {
                const int vb = (nf * 16 + l15) * 32 + sw;
                floatx4 o = O[nf];
                o = BMFMA(pf0, *(const short8*)&sVh[cur][vb], o);
                o = BMFMA(pf1, *(const short8*)&sVh[cur][2048 + vb], o);
                O[nf] = o;
            }
            cur ^= 1;
        }

        // ---- finalize this segment: divide by l, store plain bf16 ----
        float rl[4];
#pragma unroll
        for (int r = 0; r < 4; ++r) rl[r] = 1.0f / lAcc[r];
#pragma unroll
        for (int nf = 0; nf < 4; ++nf)
#pragma unroll
            for (int r = 0; r < 4; ++r) {
                const int tok = b * SEQ + qt * 64 + w * 16 + quad * 4 + r;
                const int col = h * 64 + nf * 16 + l15;
                attnx[(size_t)tok * 1024 + col] = f2bf(O[nf][r] * rl[r]);
            }
    }
}

// ---------------------------------------------------------------------------
extern "C" void kernel_launch(void* const* d_in, const int* in_sizes, int n_in,
                              void* d_out, int out_size, void* d_ws, size_t ws_size,
                              hipStream_t stream)
{
    const float* x    = (const float*)d_in[0];
    const int*   am   = (const int*)d_in[1];
    const float* Wqkv = (const float*)d_in[2];
    const float* bqkv = (const float*)d_in[3];
    const float* Wout = (const float*)d_in[4];
    const float* bout = (const float*)d_in[5];
    float* out = (float*)d_out;

    // ws layout (113.2 MB, unchanged footprint):
    //   Bt 12.58MB | qkv fp32 50.33MB (start reused as attnx bf16 after prep) |
    //   Qh | Ql-slot (now: Bt2 4.19MB + mbits 512B) | Kh Kl Vh 8.39MB each;
    //   Ax aliases Vh pre-prep
    char* ws = (char*)d_ws;
    unsigned short* Bt = (unsigned short*)ws;
    float* qkv = (float*)(ws + 12582912);
    unsigned short* attnx = (unsigned short*)qkv;        // alias: qkv dead after prep
    unsigned short* Qh = (unsigned short*)(ws + 62914560);
    unsigned short* Bt2 = Qh + 4194304;                  // Ql slot, first 4.19MB
    unsigned long long* mbits = (unsigned long long*)(Bt2 + 2097152);
    unsigned short* Kh = Qh + 2 * 4194304;
    unsigned short* Kl = Kh + 4194304;
    unsigned short* Vh = Kl + 4194304;
    unsigned short* Ax = Vh;                             // alias: dead after gemm1

    // 0) split x -> Ax, W_qkv -> Bt, W_out -> Bt2, mask -> mbits (one launch)
    split_inputs<<<8193, 256, 0, stream>>>(x, Wqkv, Wout, am, Ax, Bt, Bt2, mbits);

    // 1a) qkv[:, 0:2048] (Q,K cols) = x @ Wqkv + b   (fused-x3, fp32-grade)
    gemm_mfma_x3f<2, 2, 4, 4><<<512, 256, 0, stream>>>(
        Ax, Bt, bqkv, qkv, 3072, 16);
    // 1b) qkv[:, 2048:3072] (V cols) = x @ Wqkv + b  (single bf16 — V is
    //     truncated to bf16 in flash anyway)
    gemm_mfma_s<2, 2, 4, 4><<<256, 256, 0, stream>>>(
        Ax, 2048, Bt + (size_t)2048 * 2048, 2048,
        bqkv + 2048, qkv + 2048, 3072, 8);

    // 2) RoPE + scale + split (Q hi, K hi+lo, V hi transposed)
    prep_qkv<<<1024, 256, 0, stream>>>(qkv, Qh, Kh, Kl, Vh);

    // 3) MFMA flash attention -> attnx (paired q-tiles, dbuf staging)
    flash_mfma<<<512, 256, 0, stream>>>(Qh, Kh, Kl, Vh, mbits, attnx);

    // 4) out = attn @ W_out + b  (single bf16, Bt2 prepared in step 0)
    gemm_mfma_s<2, 2, 4, 4><<<256, 256, 0, stream>>>(
        attnx, 1024, Bt2, 2048, bout, out, 1024, 8);
}

// Round 2
// 245.234 us; speedup vs baseline: 1.0422x; 1.0422x over previous
//
#include <hip/hip_runtime.h>
#include <math.h>
#include <stdint.h>

#define D_MODEL 1024
#define N_HEADS 16
#define HEAD_DIM 64
#define BATCH 2
#define SEQ 2048
#define TOKENS (BATCH * SEQ)   // 4096

typedef __attribute__((ext_vector_type(8))) short short8;   // 8 bf16 = 4 VGPRs
typedef __attribute__((ext_vector_type(4))) float floatx4;  // MFMA C/D frag

#define BMFMA(a, b, c) __builtin_amdgcn_mfma_f32_16x16x32_bf16(a, b, c, 0, 0, 0)

__device__ __forceinline__ unsigned short f2bf(float f) {
    uint32_t u = __float_as_uint(f);
    u += 0x7fffu + ((u >> 16) & 1u);
    return (unsigned short)(u >> 16);
}
__device__ __forceinline__ float bf2f(unsigned short h) {
    return __uint_as_float(((uint32_t)h) << 16);
}

// async global -> LDS, 16B per lane; LDS dest = wave-uniform base + lane*16
#define GLD_LDS16(gp, lp) __builtin_amdgcn_global_load_lds(                 \
    (const __attribute__((address_space(1))) void*)(gp),                    \
    (__attribute__((address_space(3))) void*)(lp), 16, 0, 0)

// ---------------------------------------------------------------------------
// Merged input prep:
//   blocks [0,4096)      : x -> Ax (bf16 hi|lo)
//   blocks [4096,7168)   : W_qkv -> Bt (transpose + hi|lo split)
//   blocks [7168,8192)   : W_out -> Bt2 (transpose + hi|lo split)
//   block  8192          : attention_mask -> 64-bit per-k-tile bitmask
// ---------------------------------------------------------------------------
__global__ __launch_bounds__(256) void split_inputs(
    const float* __restrict__ X, const float* __restrict__ Wqkv,
    const float* __restrict__ Wout, const int* __restrict__ am,
    unsigned short* __restrict__ Ax, unsigned short* __restrict__ Bt,
    unsigned short* __restrict__ Bt2, unsigned long long* __restrict__ mbits)
{
    __shared__ float t[32][33];
    const int tid = threadIdx.x;
    const int bid = blockIdx.x;
    if (bid < 4096) {
        const int idx = bid * 256 + tid;
        const int row = idx >> 8;
        const int c = (idx & 255) * 4;
        float4 v = *(const float4*)(X + (size_t)row * 1024 + c);
        float f[4] = {v.x, v.y, v.z, v.w};
        uint32_t hp[2], lp[2];
#pragma unroll
        for (int j = 0; j < 2; ++j) {
            unsigned short h0 = f2bf(f[2 * j]), h1 = f2bf(f[2 * j + 1]);
            hp[j] = (uint32_t)h0 | ((uint32_t)h1 << 16);
            lp[j] = (uint32_t)f2bf(f[2 * j] - bf2f(h0)) |
                    ((uint32_t)f2bf(f[2 * j + 1] - bf2f(h1)) << 16);
        }
        *(uint2*)(Ax + (size_t)row * 2048 + c) = make_uint2(hp[0], hp[1]);
        *(uint2*)(Ax + (size_t)row * 2048 + 1024 + c) = make_uint2(lp[0], lp[1]);
    } else if (bid < 7168) {
        const int id = bid - 4096;                 // 0..3071
        const int n0 = (id % 96) * 32, k0 = (id / 96) * 32;
        const int c = tid & 31, r = tid >> 5;
#pragma unroll
        for (int i = 0; i < 4; ++i)
            t[r + 8 * i][c] = Wqkv[(size_t)(k0 + r + 8 * i) * 3072 + n0 + c];
        __syncthreads();
#pragma unroll
        for (int i = 0; i < 4; ++i) {
            int dn = r + 8 * i;
            float f = t[c][dn];
            unsigned short hi = f2bf(f);
            unsigned short lo = f2bf(f - bf2f(hi));
            size_t row = (size_t)(n0 + dn) * 2048;
            Bt[row + k0 + c] = hi;
            Bt[row + 1024 + k0 + c] = lo;
        }
    } else if (bid < 8192) {
        const int id = bid - 7168;                 // 0..1023: W_out 32x32 tiles
        const int n0 = (id & 31) * 32, k0 = (id >> 5) * 32;
        const int c = tid & 31, r = tid >> 5;
#pragma unroll
        for (int i = 0; i < 4; ++i)
            t[r + 8 * i][c] = Wout[(size_t)(k0 + r + 8 * i) * 1024 + n0 + c];
        __syncthreads();
#pragma unroll
        for (int i = 0; i < 4; ++i) {
            int dn = r + 8 * i;
            float f = t[c][dn];
            unsigned short hi = f2bf(f);
            unsigned short lo = f2bf(f - bf2f(hi));
            size_t row = (size_t)(n0 + dn) * 2048;
            Bt2[row + k0 + c] = hi;
            Bt2[row + 1024 + k0 + c] = lo;
        }
    } else {
        // mask bitmap: one uint64 per 64-token tile (B*SEQ/64 = 64 tiles)
        if (tid < 64) {
            const int* a = am + tid * 64;
            unsigned long long m = 0ull;
            for (int j = 0; j < 64; ++j)
                m |= (unsigned long long)(a[j] != 0 ? 1u : 0u) << j;
            mbits[tid] = m;
        }
    }
}

// ---------------------------------------------------------------------------
// FUSED x3 bf16 MFMA GEMM (R6 structure), 1D grid + 8-wide M-supertile
// swizzle. A: Ax [M][2048] hi|lo. B: Bt rows [n][2048] hi|lo. C stride ldc.
// ---------------------------------------------------------------------------
template<int WM, int WN, int FM, int FN>
__global__ __launch_bounds__(256) void gemm_mfma_x3f(
    const unsigned short* __restrict__ Ax, const unsigned short* __restrict__ Bt,
    const float* __restrict__ bias, float* __restrict__ C, int ldc, int nTiles)
{
    constexpr int BM = WM * FM * 16;
    constexpr int BN = WN * FN * 16;
    constexpr int NA = BM / 64;
    constexpr int NB = BN / 64;

    __shared__ __align__(16) unsigned short sAh[BM * 32];
    __shared__ __align__(16) unsigned short sAl[BM * 32];
    __shared__ __align__(16) unsigned short sBh[BN * 32];
    __shared__ __align__(16) unsigned short sBl[BN * 32];

    const int tid = threadIdx.x;
    const int w = tid >> 6, lane = tid & 63;
    const int l15 = lane & 15, quad = lane >> 4;
    const int wm = w / WN, wn = w % WN;

    const int lin = blockIdx.x;
    const int msuper = lin / (8 * nTiles);
    const int rem = lin % (8 * nTiles);
    const int m0 = (msuper * 8 + (rem & 7)) * BM;
    const int n0 = (rem >> 3) * BN;

    const int ch = (lane & 3) ^ ((lane >> 3) & 3);       // staging swizzle
    const int sw = (quad ^ ((l15 >> 1) & 3)) * 8;        // frag-read swizzle

    const unsigned short* aG[NA];
    const unsigned short* bG[NB];
#pragma unroll
    for (int i = 0; i < NA; ++i)
        aG[i] = Ax + (size_t)(m0 + (w * NA + i) * 16 + (lane >> 2)) * 2048
                   + ch * 8;
#pragma unroll
    for (int i = 0; i < NB; ++i)
        bG[i] = Bt + (size_t)(n0 + (w * NB + i) * 16 + (lane >> 2)) * 2048
                   + ch * 8;

    floatx4 acc[FM][FN];
#pragma unroll
    for (int fm = 0; fm < FM; ++fm)
#pragma unroll
        for (int fn = 0; fn < FN; ++fn) acc[fm][fn] = (floatx4)0.f;

    for (int ks = 0; ks < 32; ++ks) {
        const int ko = ks * 32;          // hi at ko, lo at 1024+ko
        __syncthreads();
#pragma unroll
        for (int i = 0; i < NA; ++i) {
            GLD_LDS16(aG[i] + ko,        sAh + (w * NA + i) * 512);
            GLD_LDS16(aG[i] + 1024 + ko, sAl + (w * NA + i) * 512);
        }
#pragma unroll
        for (int i = 0; i < NB; ++i) {
            GLD_LDS16(bG[i] + ko,        sBh + (w * NB + i) * 512);
            GLD_LDS16(bG[i] + 1024 + ko, sBl + (w * NB + i) * 512);
        }
        __syncthreads();

        short8 ah[FM], al[FM], bh[FN], bl[FN];
#pragma unroll
        for (int fm = 0; fm < FM; ++fm) {
            const int off = ((wm * FM + fm) * 16 + l15) * 32 + sw;
            ah[fm] = *(const short8*)&sAh[off];
            al[fm] = *(const short8*)&sAl[off];
        }
#pragma unroll
        for (int fn = 0; fn < FN; ++fn) {
            const int off = ((wn * FN + fn) * 16 + l15) * 32 + sw;
            bh[fn] = *(const short8*)&sBh[off];
            bl[fn] = *(const short8*)&sBl[off];
        }
#pragma unroll
        for (int fm = 0; fm < FM; ++fm)
#pragma unroll
            for (int fn = 0; fn < FN; ++fn) {
                floatx4 a = acc[fm][fn];
                a = BMFMA(ah[fm], bh[fn], a);
                a = BMFMA(ah[fm], bl[fn], a);
                a = BMFMA(al[fm], bh[fn], a);
                acc[fm][fn] = a;
            }
    }

#pragma unroll
    for (int fm = 0; fm < FM; ++fm)
#pragma unroll
        for (int fn = 0; fn < FN; ++fn) {
            int col = n0 + (wn * FN + fn) * 16 + l15;
            float bv = bias[col];
#pragma unroll
            for (int r = 0; r < 4; ++r) {
                int row = m0 + (wm * FM + fm) * 16 + quad * 4 + r;
                C[(size_t)row * ldc + col] = acc[fm][fn][r] + bv;
            }
        }
}

// ---------------------------------------------------------------------------
// Single-precision bf16 MFMA GEMM. BK=64, runtime A/B/C strides.
// ---------------------------------------------------------------------------
template<int WM, int WN, int FM, int FN>
__global__ __launch_bounds__(256) void gemm_mfma_s(
    const unsigned short* __restrict__ A, int lda,
    const unsigned short* __restrict__ Bt, int ldb,
    const float* __restrict__ bias, float* __restrict__ C, int ldc, int nTiles)
{
    constexpr int BM = WM * FM * 16;
    constexpr int BN = WN * FN * 16;
    constexpr int NA = BM / 64;
    constexpr int NB = BN / 64;

    __shared__ __align__(16) unsigned short sA0[BM * 32];
    __shared__ __align__(16) unsigned short sA1[BM * 32];
    __shared__ __align__(16) unsigned short sB0[BN * 32];
    __shared__ __align__(16) unsigned short sB1[BN * 32];

    const int tid = threadIdx.x;
    const int w = tid >> 6, lane = tid & 63;
    const int l15 = lane & 15, quad = lane >> 4;
    const int wm = w / WN, wn = w % WN;

    const int lin = blockIdx.x;
    const int msuper = lin / (8 * nTiles);
    const int rem = lin % (8 * nTiles);
    const int m0 = (msuper * 8 + (rem & 7)) * BM;
    const int n0 = (rem >> 3) * BN;

    const int ch = (lane & 3) ^ ((lane >> 3) & 3);
    const int sw = (quad ^ ((l15 >> 1) & 3)) * 8;

    const unsigned short* aG[NA];
    const unsigned short* bG[NB];
#pragma unroll
    for (int i = 0; i < NA; ++i)
        aG[i] = A + (size_t)(m0 + (w * NA + i) * 16 + (lane >> 2)) * lda + ch * 8;
#pragma unroll
    for (int i = 0; i < NB; ++i)
        bG[i] = Bt + (size_t)(n0 + (w * NB + i) * 16 + (lane >> 2)) * ldb + ch * 8;

    floatx4 acc[FM][FN];
#pragma unroll
    for (int fm = 0; fm < FM; ++fm)
#pragma unroll
        for (int fn = 0; fn < FN; ++fn) acc[fm][fn] = (floatx4)0.f;

    for (int ks = 0; ks < 16; ++ks) {
        const int ko = ks * 64;
        __syncthreads();
#pragma unroll
        for (int i = 0; i < NA; ++i) {
            GLD_LDS16(aG[i] + ko,      sA0 + (w * NA + i) * 512);
            GLD_LDS16(aG[i] + ko + 32, sA1 + (w * NA + i) * 512);
        }
#pragma unroll
        for (int i = 0; i < NB; ++i) {
            GLD_LDS16(bG[i] + ko,      sB0 + (w * NB + i) * 512);
            GLD_LDS16(bG[i] + ko + 32, sB1 + (w * NB + i) * 512);
        }
        __syncthreads();

        short8 a0[FM], a1[FM], b0[FN], b1[FN];
#pragma unroll
        for (int fm = 0; fm < FM; ++fm) {
            const int off = ((wm * FM + fm) * 16 + l15) * 32 + sw;
            a0[fm] = *(const short8*)&sA0[off];
            a1[fm] = *(const short8*)&sA1[off];
        }
#pragma unroll
        for (int fn = 0; fn < FN; ++fn) {
            const int off = ((wn * FN + fn) * 16 + l15) * 32 + sw;
            b0[fn] = *(const short8*)&sB0[off];
            b1[fn] = *(const short8*)&sB1[off];
        }
#pragma unroll
        for (int fm = 0; fm < FM; ++fm)
#pragma unroll
            for (int fn = 0; fn < FN; ++fn) {
                floatx4 a = acc[fm][fn];
                a = BMFMA(a0[fm], b0[fn], a);
                a = BMFMA(a1[fm], b1[fn], a);
                acc[fm][fn] = a;
            }
    }

#pragma unroll
    for (int fm = 0; fm < FM; ++fm)
#pragma unroll
        for (int fn = 0; fn < FN; ++fn) {
            int col = n0 + (wn * FN + fn) * 16 + l15;
            float bv = bias[col];
#pragma unroll
            for (int r = 0; r < 4; ++r) {
                int row = m0 + (wm * FM + fm) * 16 + quad * 4 + r;
                C[(size_t)row * ldc + col] = acc[fm][fn][r] + bv;
            }
        }
}

// ---------------------------------------------------------------------------
// prep_qkv: RoPE + 1/8 q-scale + bf16 split. Q hi / K hi+lo [bh][t][64];
// V hi [bh][d][2048] transposed.
// ---------------------------------------------------------------------------
__global__ __launch_bounds__(256) void prep_qkv(
    const float* __restrict__ qkv,
    unsigned short* __restrict__ Qh,
    unsigned short* __restrict__ Kh, unsigned short* __restrict__ Kl,
    unsigned short* __restrict__ Vh)
{
    __shared__ float vt[64][65];
    const int tid = threadIdx.x;
    const int lin = blockIdx.x;
    const int tt = lin & 31, bh = lin >> 5;
    const int b = bh >> 4, h = bh & 15;
    const int r = tid >> 2;
    const int dblk = (tid & 3) * 16;
    const int tg = tt * 64 + r;
    const size_t src = (size_t)(b * SEQ + tg) * 3072 + h * 64 + dblk;
    const size_t dst = ((size_t)bh * SEQ + tg) * 64 + dblk;

    float q[16], k[16], v[16];
#pragma unroll
    for (int i = 0; i < 4; ++i) {
        *(float4*)&q[4 * i] = *(const float4*)(qkv + src + 4 * i);
        *(float4*)&k[4 * i] = *(const float4*)(qkv + src + 1024 + 4 * i);
        *(float4*)&v[4 * i] = *(const float4*)(qkv + src + 2048 + 4 * i);
    }
#pragma unroll
    for (int j = 0; j < 16; j += 2) {
        int pr = (dblk + j) >> 1;
        double e = (double)(2 * pr) / 64.0;
        float inv = (float)exp2(-e * 13.287712379549449);
        float ang = (float)tg * inv;
        float s, c;
        __sincosf(ang, &s, &c);
        float qe = q[j], qo = q[j + 1];
        q[j] = qe * c - qo * s; q[j + 1] = qe * s + qo * c;
        float ke = k[j], ko = k[j + 1];
        k[j] = ke * c - ko * s; k[j + 1] = ke * s + ko * c;
    }
    uint32_t ph[8], pl[8];
#pragma unroll
    for (int j = 0; j < 8; ++j) {
        float f0 = q[2 * j] * 0.125f, f1 = q[2 * j + 1] * 0.125f;
        ph[j] = (uint32_t)f2bf(f0) | ((uint32_t)f2bf(f1) << 16);
    }
    *(uint4*)(Qh + dst) = *(uint4*)&ph[0]; *(uint4*)(Qh + dst + 8) = *(uint4*)&ph[4];
#pragma unroll
    for (int j = 0; j < 8; ++j) {
        float f0 = k[2 * j], f1 = k[2 * j + 1];
        unsigned short h0 = f2bf(f0), h1 = f2bf(f1);
        ph[j] = (uint32_t)h0 | ((uint32_t)h1 << 16);
        pl[j] = (uint32_t)f2bf(f0 - bf2f(h0)) | ((uint32_t)f2bf(f1 - bf2f(h1)) << 16);
    }
    *(uint4*)(Kh + dst) = *(uint4*)&ph[0]; *(uint4*)(Kh + dst + 8) = *(uint4*)&ph[4];
    *(uint4*)(Kl + dst) = *(uint4*)&pl[0]; *(uint4*)(Kl + dst + 8) = *(uint4*)&pl[4];

#pragma unroll
    for (int j = 0; j < 16; ++j) vt[r][dblk + j] = v[j];
    __syncthreads();
    const int d2 = tid >> 2;
    const int tb = (tid & 3) * 16;
#pragma unroll
    for (int j = 0; j < 8; ++j) {
        float f0 = vt[tb + 2 * j][d2], f1 = vt[tb + 2 * j + 1][d2];
        ph[j] = (uint32_t)f2bf(f0) | ((uint32_t)f2bf(f1) << 16);
    }
    const size_t vdst = ((size_t)bh * 64 + d2) * SEQ + tt * 64 + tb;
    *(uint4*)(Vh + vdst) = *(uint4*)&ph[0]; *(uint4*)(Vh + vdst + 8) = *(uint4*)&ph[4];
}

// ---------------------------------------------------------------------------
// MFMA flash attention, R12: R10 loop structure (single-buffer 32KB LDS,
// 1024 blocks, 4 blocks/CU) + VALU-chain cuts:
//  - v_cvt_pk_bf16_f32 P pack (16 f2bf ~80 VALU -> 8 cvt_pk, identical RNE)
//  - wave-uniform full-mask fast path (ballot once; skips per-element bit
//    tests + 2 shfl/iter on all-ones masks, still correct for any mask)
//  - mask bitmap in lane registers (R11), zero VMEM on compute path
//  - bijective XCD swizzle: 4 bh per XCD (3MB K/V -> per-XCD L2)
// ---------------------------------------------------------------------------
__global__ __launch_bounds__(256, 4) void flash_mfma(
    const unsigned short* __restrict__ Qh,
    const unsigned short* __restrict__ Kh, const unsigned short* __restrict__ Kl,
    const unsigned short* __restrict__ Vh,
    const unsigned long long* __restrict__ mbits,
    unsigned short* __restrict__ attnx)
{
    __shared__ __align__(16) unsigned short sKh[4096];
    __shared__ __align__(16) unsigned short sKl[4096];
    __shared__ __align__(16) unsigned short sVh[4096];
    __shared__ __align__(16) unsigned short sP[4096];

    const int tid = threadIdx.x;
    const int lane = tid & 63, w = tid >> 6;
    const int l15 = lane & 15, quad = lane >> 4;
    const int lin0 = blockIdx.x;
    const int xcd = lin0 & 7, idx = lin0 >> 3;     // 1024 = 8 XCD * 128
    const int bh = xcd * 4 + (idx & 3);            // 4 bh per XCD (L2-resident)
    const int qt = 31 - (idx >> 2);                // heavy q-tiles start first
    const int b = bh >> 4, h = bh & 15;
    const int sw = (quad ^ ((l15 >> 1) & 3)) * 8;
    const int ch = (lane & 3) ^ ((lane >> 3) & 3);
    unsigned short* pbase = sP + w * 1024;

    short8 ones;
#pragma unroll
    for (int j = 0; j < 8; ++j) ones[j] = (short)0x3F80;  // bf16 1.0

    const size_t qb = ((size_t)bh * SEQ + qt * 64 + w * 16 + l15) * 64 + quad * 8;
    const short8 qh0 = *(const short8*)(Qh + qb);
    const short8 qh1 = *(const short8*)(Qh + qb + 32);

    // lane l (<32) holds the mask word of k-tile l for this batch
    unsigned int mlo = 0xffffffffu, mhi = 0xffffffffu;
    if (lane < 32) {
        unsigned long long mw = mbits[b * 32 + lane];
        mlo = (unsigned int)mw;
        mhi = (unsigned int)(mw >> 32);
    }
    const bool fullmask =
        (__ballot((mlo & mhi) == 0xffffffffu) == ~0ull);

    const size_t kRow0 = ((size_t)bh * SEQ + w * 16 + (lane >> 2)) * 64 + ch * 8;
    const size_t vRow  = ((size_t)bh * 64 + w * 16 + (lane >> 2)) * SEQ + ch * 8;

    floatx4 O[4];
    floatx4 lAcc = (floatx4)0.f;
#pragma unroll
    for (int nf = 0; nf < 4; ++nf) O[nf] = (floatx4)0.f;

    const int mg = qt * 64 + w * 16 + l15;

    for (int kt = 0; kt <= qt; ++kt) {
        __syncthreads();
        {
            const size_t kg = kRow0 + (size_t)kt * 64 * 64;
            const size_t vg = vRow + kt * 64;
            GLD_LDS16(Kh + kg,      sKh + w * 512);
            GLD_LDS16(Kh + kg + 32, sKh + 2048 + w * 512);
            GLD_LDS16(Kl + kg,      sKl + w * 512);
            GLD_LDS16(Kl + kg + 32, sKl + 2048 + w * 512);
            GLD_LDS16(Vh + vg,      sVh + w * 512);
            GLD_LDS16(Vh + vg + 32, sVh + 2048 + w * 512);
        }
        __syncthreads();

        const bool diag = (kt == qt);
        unsigned int wlo = 0xffffffffu, whi = 0xffffffffu;
        if (!fullmask) {
            wlo = (unsigned int)__shfl((int)mlo, kt);
            whi = (unsigned int)__shfl((int)mhi, kt);
        }

        // ---- S^T = K Q^T (x2), exp, pack, stage P (wave-private) ----
#pragma unroll
        for (int nf = 0; nf < 4; ++nf) {
            const int base = (nf * 16 + l15) * 32 + sw;
            const short8 kh0 = *(const short8*)&sKh[base];
            const short8 kh1 = *(const short8*)&sKh[2048 + base];
            const short8 kl0 = *(const short8*)&sKl[base];
            const short8 kl1 = *(const short8*)&sKl[2048 + base];
            floatx4 s = (floatx4)0.f;
            s = BMFMA(kh0, qh0, s);
            s = BMFMA(kh1, qh1, s);
            s = BMFMA(kl0, qh0, s);
            s = BMFMA(kl1, qh1, s);

            float pv[4];
            if (fullmask && !diag) {               // wave-uniform fast path
#pragma unroll
                for (int r = 0; r < 4; ++r)
                    pv[r] = __expf(s[r] - 16.0f);
            } else {
                const int tb = kt * 64 + nf * 16 + quad * 4;
                const unsigned int msel = (nf & 2) ? whi : wlo;
                const int p4 = (nf & 1) * 16 + quad * 4;
#pragma unroll
                for (int r = 0; r < 4; ++r) {
                    bool ok = ((msel >> (p4 + r)) & 1u) != 0u;
                    if (diag) ok = ok && (tb + r <= mg);
                    pv[r] = ok ? __expf(s[r] - 16.0f) : 0.0f;
                }
            }
            uint32_t w0, w1;
            asm("v_cvt_pk_bf16_f32 %0, %1, %2" : "=v"(w0) : "v"(pv[0]), "v"(pv[1]));
            asm("v_cvt_pk_bf16_f32 %0, %1, %2" : "=v"(w1) : "v"(pv[2]), "v"(pv[3]));
            const int pos = (((nf & 1) * 2 + (quad >> 1)) ^ ((l15 >> 1) & 3));
            *(uint2*)(pbase + (nf >> 1) * 512 + l15 * 32 + pos * 8
                      + (quad & 1) * 4) = make_uint2(w0, w1);
        }

        const short8 pf0 = *(const short8*)(pbase + l15 * 32 + sw);
        const short8 pf1 = *(const short8*)(pbase + 512 + l15 * 32 + sw);

        // ---- l += P @ ones ; O += P @ Vh ----
        lAcc = BMFMA(pf0, ones, lAcc);
        lAcc = BMFMA(pf1, ones, lAcc);
#pragma unroll
        for (int nf = 0; nf < 4; ++nf) {
            const int vb = (nf * 16 + l15) * 32 + sw;
            floatx4 o = O[nf];
            o = BMFMA(pf0, *(const short8*)&sVh[vb], o);
            o = BMFMA(pf1, *(const short8*)&sVh[2048 + vb], o);
            O[nf] = o;
        }
    }

    // ---- finalize: divide by l, store plain bf16 ----
    float rl[4];
#pragma unroll
    for (int r = 0; r < 4; ++r) rl[r] = 1.0f / lAcc[r];
#pragma unroll
    for (int nf = 0; nf < 4; ++nf)
#pragma unroll
        for (int r = 0; r < 4; ++r) {
            const int tok = b * SEQ + qt * 64 + w * 16 + quad * 4 + r;
            const int col = h * 64 + nf * 16 + l15;
            attnx[(size_t)tok * 1024 + col] = f2bf(O[nf][r] * rl[r]);
        }
}

// ---------------------------------------------------------------------------
extern "C" void kernel_launch(void* const* d_in, const int* in_sizes, int n_in,
                              void* d_out, int out_size, void* d_ws, size_t ws_size,
                              hipStream_t stream)
{
    const float* x    = (const float*)d_in[0];
    const int*   am   = (const int*)d_in[1];
    const float* Wqkv = (const float*)d_in[2];
    const float* bqkv = (const float*)d_in[3];
    const float* Wout = (const float*)d_in[4];
    const float* bout = (const float*)d_in[5];
    float* out = (float*)d_out;

    // ws layout (113.2 MB, unchanged footprint):
    //   Bt 12.58MB | qkv fp32 50.33MB (reused as attnx bf16 after prep) |
    //   Qh | Ql-slot (Bt2 4.19MB + mbits 512B) | Kh Kl Vh 8.39MB each;
    //   Ax aliases Vh pre-prep
    char* ws = (char*)d_ws;
    unsigned short* Bt = (unsigned short*)ws;
    float* qkv = (float*)(ws + 12582912);
    unsigned short* attnx = (unsigned short*)qkv;        // alias: qkv dead after prep
    unsigned short* Qh = (unsigned short*)(ws + 62914560);
    unsigned short* Bt2 = Qh + 4194304;                  // Ql slot, first 4.19MB
    unsigned long long* mbits = (unsigned long long*)(Bt2 + 2097152);
    unsigned short* Kh = Qh + 2 * 4194304;
    unsigned short* Kl = Kh + 4194304;
    unsigned short* Vh = Kl + 4194304;
    unsigned short* Ax = Vh;                             // alias: dead after gemm1

    // 0) split x -> Ax, W_qkv -> Bt, W_out -> Bt2, mask -> mbits (one launch)
    split_inputs<<<8193, 256, 0, stream>>>(x, Wqkv, Wout, am, Ax, Bt, Bt2, mbits);

    // 1a) qkv[:, 0:2048] (Q,K cols) = x @ Wqkv + b   (fused-x3, fp32-grade)
    gemm_mfma_x3f<2, 2, 4, 4><<<512, 256, 0, stream>>>(
        Ax, Bt, bqkv, qkv, 3072, 16);
    // 1b) qkv[:, 2048:3072] (V cols) = x @ Wqkv + b  (single bf16)
    gemm_mfma_s<2, 2, 4, 4><<<256, 256, 0, stream>>>(
        Ax, 2048, Bt + (size_t)2048 * 2048, 2048,
        bqkv + 2048, qkv + 2048, 3072, 8);

    // 2) RoPE + scale + split (Q hi, K hi+lo, V hi transposed)
    prep_qkv<<<1024, 256, 0, stream>>>(qkv, Qh, Kh, Kl, Vh);

    // 3) MFMA flash attention -> attnx
    flash_mfma<<<1024, 256, 0, stream>>>(Qh, Kh, Kl, Vh, mbits, attnx);

    // 4) out = attn @ W_out + b  (single bf16, Bt2 prepared in step 0)
    gemm_mfma_s<2, 2, 4, 4><<<256, 256, 0, stream>>>(
        attnx, 1024, Bt2, 2048, bout, out, 1024, 8);
}

// Round 3
// 210.529 us; speedup vs baseline: 1.2140x; 1.1648x over previous
//
#include <hip/hip_runtime.h>
#include <math.h>
#include <stdint.h>

#define D_MODEL 1024
#define N_HEADS 16
#define HEAD_DIM 64
#define BATCH 2
#define SEQ 2048
#define TOKENS (BATCH * SEQ)   // 4096

typedef __attribute__((ext_vector_type(8))) short short8;      // 8 bf16
typedef __attribute__((ext_vector_type(8))) _Float16 half8;    // 8 fp16
typedef __attribute__((ext_vector_type(4))) float floatx4;     // MFMA C/D frag

#define BMFMA(a, b, c) __builtin_amdgcn_mfma_f32_16x16x32_bf16(a, b, c, 0, 0, 0)
#define HMFMA(a, b, c) __builtin_amdgcn_mfma_f32_16x16x32_f16(a, b, c, 0, 0, 0)

__device__ __forceinline__ unsigned short f2bf(float f) {
    uint32_t u = __float_as_uint(f);
    u += 0x7fffu + ((u >> 16) & 1u);
    return (unsigned short)(u >> 16);
}
__device__ __forceinline__ float bf2f(unsigned short h) {
    return __uint_as_float(((uint32_t)h) << 16);
}
__device__ __forceinline__ unsigned short f2h(float f) {
    union { _Float16 h; unsigned short u; } cv;
    cv.h = (_Float16)f;            // RNE
    return cv.u;
}
__device__ __forceinline__ float h2f(unsigned short u) {
    union { unsigned short u; _Float16 h; } cv;
    cv.u = u;
    return (float)cv.h;
}

// async global -> LDS, 16B per lane; LDS dest = wave-uniform base + lane*16
#define GLD_LDS16(gp, lp) __builtin_amdgcn_global_load_lds(                 \
    (const __attribute__((address_space(1))) void*)(gp),                    \
    (__attribute__((address_space(3))) void*)(lp), 16, 0, 0)

// ---------------------------------------------------------------------------
// Merged input prep:
//   blocks [0,4096)      : x -> Axh (fp16 hi|lo, [row][2048])
//   blocks [4096,7168)   : W_qkv -> Bt (transpose, SINGLE fp16 [n][1024])
//   blocks [7168,8192)   : W_out -> Bt2 (transpose, single bf16 [n][1024])
//   block  8192          : attention_mask -> 64-bit per-k-tile bitmask
//   blocks [8193,8209)   : RoPE cos/sin table [t][32] float2
// ---------------------------------------------------------------------------
__global__ __launch_bounds__(256) void split_inputs(
    const float* __restrict__ X, const float* __restrict__ Wqkv,
    const float* __restrict__ Wout, const int* __restrict__ am,
    unsigned short* __restrict__ Axh, unsigned short* __restrict__ Bt,
    unsigned short* __restrict__ Bt2, unsigned long long* __restrict__ mbits,
    float2* __restrict__ tab)
{
    __shared__ float t[32][33];
    const int tid = threadIdx.x;
    const int bid = blockIdx.x;
    if (bid < 4096) {
        const int idx = bid * 256 + tid;
        const int row = idx >> 8;
        const int c = (idx & 255) * 4;
        float4 v = *(const float4*)(X + (size_t)row * 1024 + c);
        float f[4] = {v.x, v.y, v.z, v.w};
        uint32_t hp[2], lp[2];
#pragma unroll
        for (int j = 0; j < 2; ++j) {
            unsigned short h0 = f2h(f[2 * j]), h1 = f2h(f[2 * j + 1]);
            hp[j] = (uint32_t)h0 | ((uint32_t)h1 << 16);
            lp[j] = (uint32_t)f2h(f[2 * j] - h2f(h0)) |
                    ((uint32_t)f2h(f[2 * j + 1] - h2f(h1)) << 16);
        }
        *(uint2*)(Axh + (size_t)row * 2048 + c) = make_uint2(hp[0], hp[1]);
        *(uint2*)(Axh + (size_t)row * 2048 + 1024 + c) = make_uint2(lp[0], lp[1]);
    } else if (bid < 7168) {
        const int id = bid - 4096;                 // 0..3071
        const int n0 = (id % 96) * 32, k0 = (id / 96) * 32;
        const int c = tid & 31, r = tid >> 5;
#pragma unroll
        for (int i = 0; i < 4; ++i)
            t[r + 8 * i][c] = Wqkv[(size_t)(k0 + r + 8 * i) * 3072 + n0 + c];
        __syncthreads();
#pragma unroll
        for (int i = 0; i < 4; ++i) {
            int dn = r + 8 * i;
            Bt[(size_t)(n0 + dn) * 1024 + k0 + c] = f2h(t[c][dn]);
        }
    } else if (bid < 8192) {
        const int id = bid - 7168;                 // 0..1023: W_out 32x32 tiles
        const int n0 = (id & 31) * 32, k0 = (id >> 5) * 32;
        const int c = tid & 31, r = tid >> 5;
#pragma unroll
        for (int i = 0; i < 4; ++i)
            t[r + 8 * i][c] = Wout[(size_t)(k0 + r + 8 * i) * 1024 + n0 + c];
        __syncthreads();
#pragma unroll
        for (int i = 0; i < 4; ++i) {
            int dn = r + 8 * i;
            Bt2[(size_t)(n0 + dn) * 1024 + k0 + c] = f2bf(t[c][dn]);
        }
    } else if (bid == 8192) {
        // mask bitmap: one uint64 per 64-token tile (B*SEQ/64 = 64 tiles)
        if (tid < 64) {
            const int* a = am + tid * 64;
            unsigned long long m = 0ull;
            for (int j = 0; j < 64; ++j)
                m |= (unsigned long long)(a[j] != 0 ? 1u : 0u) << j;
            mbits[tid] = m;
        }
    } else {
        // RoPE table: 2048 x 32 float2 (cos, sin); same arithmetic path as
        // the old prep_qkv (double exp2 -> float -> __sincosf)
        const int i = bid - 8193;                  // 0..15
#pragma unroll
        for (int e = 0; e < 16; ++e) {
            int idx = i * 4096 + e * 256 + tid;
            int tt = idx >> 5, pr = idx & 31;
            double ex = (double)(2 * pr) / 64.0;
            float inv = (float)exp2(-ex * 13.287712379549449);
            float ang = (float)tt * inv;
            float s, c;
            __sincosf(ang, &s, &c);
            tab[idx] = make_float2(c, s);
        }
    }
}

// ---------------------------------------------------------------------------
// Merged QKV projection, fp16. A = Axh [4096][2048] fp16 hi|lo.
// B = Bt [3072][1024] single fp16 (W error 2^-12 << tolerated Q-bf16 noise).
//   blocks [0,512)   : x2 path (Ah*B + Al*B), N-cols [0,2048)  (Q,K)
//   blocks [512,768) : x1 path (Ah*B),        N-cols [2048,3072) (V)
// 128x128 tiles, BK=64, LDS 48KB -> 3 blocks/CU, all 768 co-resident.
// ---------------------------------------------------------------------------
__global__ __launch_bounds__(256) void gemm_qkv_f16(
    const unsigned short* __restrict__ Axh, const unsigned short* __restrict__ Bt,
    const float* __restrict__ bias, float* __restrict__ C)
{
    __shared__ __align__(16) unsigned short sAh0[4096], sAh1[4096];
    __shared__ __align__(16) unsigned short sAl0[4096], sAl1[4096];
    __shared__ __align__(16) unsigned short sB0[4096],  sB1[4096];

    const int tid = threadIdx.x;
    const int w = tid >> 6, lane = tid & 63;
    const int l15 = lane & 15, quad = lane >> 4;
    const int wm = w >> 1, wn = w & 1;

    const bool qk = blockIdx.x < 512;
    const int lin = qk ? blockIdx.x : blockIdx.x - 512;
    const int nT = qk ? 16 : 8;
    const int msuper = lin / (8 * nT);
    const int rem = lin % (8 * nT);
    const int m0 = (msuper * 8 + (rem & 7)) * 128;
    const int n0 = (qk ? 0 : 2048) + (rem >> 3) * 128;

    const int ch = (lane & 3) ^ ((lane >> 3) & 3);       // staging swizzle
    const int sw = (quad ^ ((l15 >> 1) & 3)) * 8;        // frag-read swizzle

    const unsigned short* aG[2];
    const unsigned short* bG[2];
#pragma unroll
    for (int i = 0; i < 2; ++i) {
        aG[i] = Axh + (size_t)(m0 + (w * 2 + i) * 16 + (lane >> 2)) * 2048
                    + ch * 8;
        bG[i] = Bt + (size_t)(n0 + (w * 2 + i) * 16 + (lane >> 2)) * 1024
                   + ch * 8;
    }

    floatx4 acc[4][4];
#pragma unroll
    for (int fm = 0; fm < 4; ++fm)
#pragma unroll
        for (int fn = 0; fn < 4; ++fn) acc[fm][fn] = (floatx4)0.f;

    for (int ks = 0; ks < 16; ++ks) {
        const int ko = ks * 64;                  // hi at ko, lo at 1024+ko
        __syncthreads();
#pragma unroll
        for (int i = 0; i < 2; ++i) {
            GLD_LDS16(aG[i] + ko,        sAh0 + (w * 2 + i) * 512);
            GLD_LDS16(aG[i] + ko + 32,   sAh1 + (w * 2 + i) * 512);
            GLD_LDS16(bG[i] + ko,        sB0 + (w * 2 + i) * 512);
            GLD_LDS16(bG[i] + ko + 32,   sB1 + (w * 2 + i) * 512);
        }
        if (qk) {
#pragma unroll
            for (int i = 0; i < 2; ++i) {
                GLD_LDS16(aG[i] + 1024 + ko,      sAl0 + (w * 2 + i) * 512);
                GLD_LDS16(aG[i] + 1024 + ko + 32, sAl1 + (w * 2 + i) * 512);
            }
        }
        __syncthreads();

        half8 b0[4], b1[4];
#pragma unroll
        for (int fn = 0; fn < 4; ++fn) {
            const int off = ((wn * 4 + fn) * 16 + l15) * 32 + sw;
            b0[fn] = *(const half8*)&sB0[off];
            b1[fn] = *(const half8*)&sB1[off];
        }
#pragma unroll
        for (int fm = 0; fm < 4; ++fm) {
            const int off = ((wm * 4 + fm) * 16 + l15) * 32 + sw;
            half8 a0 = *(const half8*)&sAh0[off];
            half8 a1 = *(const half8*)&sAh1[off];
#pragma unroll
            for (int fn = 0; fn < 4; ++fn) {
                floatx4 a = acc[fm][fn];
                a = HMFMA(a0, b0[fn], a);
                a = HMFMA(a1, b1[fn], a);
                acc[fm][fn] = a;
            }
        }
        if (qk) {
#pragma unroll
            for (int fm = 0; fm < 4; ++fm) {
                const int off = ((wm * 4 + fm) * 16 + l15) * 32 + sw;
                half8 a0 = *(const half8*)&sAl0[off];
                half8 a1 = *(const half8*)&sAl1[off];
#pragma unroll
                for (int fn = 0; fn < 4; ++fn) {
                    floatx4 a = acc[fm][fn];
                    a = HMFMA(a0, b0[fn], a);
                    a = HMFMA(a1, b1[fn], a);
                    acc[fm][fn] = a;
                }
            }
        }
    }

#pragma unroll
    for (int fm = 0; fm < 4; ++fm)
#pragma unroll
        for (int fn = 0; fn < 4; ++fn) {
            int col = n0 + (wn * 4 + fn) * 16 + l15;
            float bv = bias[col];
#pragma unroll
            for (int r = 0; r < 4; ++r) {
                int row = m0 + (wm * 4 + fm) * 16 + quad * 4 + r;
                C[(size_t)row * 3072 + col] = acc[fm][fn][r] + bv;
            }
        }
}

// ---------------------------------------------------------------------------
// Single-precision bf16 MFMA GEMM. BK=64, runtime A/B/C strides.
// Used for the out-projection (attnx bf16 x Bt2 bf16).
// ---------------------------------------------------------------------------
template<int WM, int WN, int FM, int FN>
__global__ __launch_bounds__(256) void gemm_mfma_s(
    const unsigned short* __restrict__ A, int lda,
    const unsigned short* __restrict__ Bt, int ldb,
    const float* __restrict__ bias, float* __restrict__ C, int ldc, int nTiles)
{
    constexpr int BM = WM * FM * 16;
    constexpr int BN = WN * FN * 16;
    constexpr int NA = BM / 64;
    constexpr int NB = BN / 64;

    __shared__ __align__(16) unsigned short sA0[BM * 32];
    __shared__ __align__(16) unsigned short sA1[BM * 32];
    __shared__ __align__(16) unsigned short sB0[BN * 32];
    __shared__ __align__(16) unsigned short sB1[BN * 32];

    const int tid = threadIdx.x;
    const int w = tid >> 6, lane = tid & 63;
    const int l15 = lane & 15, quad = lane >> 4;
    const int wm = w / WN, wn = w % WN;

    const int lin = blockIdx.x;
    const int msuper = lin / (8 * nTiles);
    const int rem = lin % (8 * nTiles);
    const int m0 = (msuper * 8 + (rem & 7)) * BM;
    const int n0 = (rem >> 3) * BN;

    const int ch = (lane & 3) ^ ((lane >> 3) & 3);
    const int sw = (quad ^ ((l15 >> 1) & 3)) * 8;

    const unsigned short* aG[NA];
    const unsigned short* bG[NB];
#pragma unroll
    for (int i = 0; i < NA; ++i)
        aG[i] = A + (size_t)(m0 + (w * NA + i) * 16 + (lane >> 2)) * lda + ch * 8;
#pragma unroll
    for (int i = 0; i < NB; ++i)
        bG[i] = Bt + (size_t)(n0 + (w * NB + i) * 16 + (lane >> 2)) * ldb + ch * 8;

    floatx4 acc[FM][FN];
#pragma unroll
    for (int fm = 0; fm < FM; ++fm)
#pragma unroll
        for (int fn = 0; fn < FN; ++fn) acc[fm][fn] = (floatx4)0.f;

    for (int ks = 0; ks < 16; ++ks) {
        const int ko = ks * 64;
        __syncthreads();
#pragma unroll
        for (int i = 0; i < NA; ++i) {
            GLD_LDS16(aG[i] + ko,      sA0 + (w * NA + i) * 512);
            GLD_LDS16(aG[i] + ko + 32, sA1 + (w * NA + i) * 512);
        }
#pragma unroll
        for (int i = 0; i < NB; ++i) {
            GLD_LDS16(bG[i] + ko,      sB0 + (w * NB + i) * 512);
            GLD_LDS16(bG[i] + ko + 32, sB1 + (w * NB + i) * 512);
        }
        __syncthreads();

        short8 a0[FM], a1[FM], b0[FN], b1[FN];
#pragma unroll
        for (int fm = 0; fm < FM; ++fm) {
            const int off = ((wm * FM + fm) * 16 + l15) * 32 + sw;
            a0[fm] = *(const short8*)&sA0[off];
            a1[fm] = *(const short8*)&sA1[off];
        }
#pragma unroll
        for (int fn = 0; fn < FN; ++fn) {
            const int off = ((wn * FN + fn) * 16 + l15) * 32 + sw;
            b0[fn] = *(const short8*)&sB0[off];
            b1[fn] = *(const short8*)&sB1[off];
        }
#pragma unroll
        for (int fm = 0; fm < FM; ++fm)
#pragma unroll
            for (int fn = 0; fn < FN; ++fn) {
                floatx4 a = acc[fm][fn];
                a = BMFMA(a0[fm], b0[fn], a);
                a = BMFMA(a1[fm], b1[fn], a);
                acc[fm][fn] = a;
            }
    }

#pragma unroll
    for (int fm = 0; fm < FM; ++fm)
#pragma unroll
        for (int fn = 0; fn < FN; ++fn) {
            int col = n0 + (wn * FN + fn) * 16 + l15;
            float bv = bias[col];
#pragma unroll
            for (int r = 0; r < 4; ++r) {
                int row = m0 + (wm * FM + fm) * 16 + quad * 4 + r;
                C[(size_t)row * ldc + col] = acc[fm][fn][r] + bv;
            }
        }
}

// ---------------------------------------------------------------------------
// prep_qkv: RoPE (table-driven) + 1/8 q-scale + bf16 split.
// Q hi / K hi+lo [bh][t][64]; V hi [bh][d][2048] transposed.
// ---------------------------------------------------------------------------
__global__ __launch_bounds__(256) void prep_qkv(
    const float* __restrict__ qkv, const float2* __restrict__ tab,
    unsigned short* __restrict__ Qh,
    unsigned short* __restrict__ Kh, unsigned short* __restrict__ Kl,
    unsigned short* __restrict__ Vh)
{
    __shared__ float vt[64][65];
    const int tid = threadIdx.x;
    const int lin = blockIdx.x;
    const int tt = lin & 31, bh = lin >> 5;
    const int b = bh >> 4, h = bh & 15;
    const int r = tid >> 2;
    const int dblk = (tid & 3) * 16;
    const int tg = tt * 64 + r;
    const size_t src = (size_t)(b * SEQ + tg) * 3072 + h * 64 + dblk;
    const size_t dst = ((size_t)bh * SEQ + tg) * 64 + dblk;

    float q[16], k[16], v[16];
#pragma unroll
    for (int i = 0; i < 4; ++i) {
        *(float4*)&q[4 * i] = *(const float4*)(qkv + src + 4 * i);
        *(float4*)&k[4 * i] = *(const float4*)(qkv + src + 1024 + 4 * i);
        *(float4*)&v[4 * i] = *(const float4*)(qkv + src + 2048 + 4 * i);
    }
    float2 cs[8];
#pragma unroll
    for (int i = 0; i < 4; ++i)
        *(float4*)&cs[2 * i] = *(const float4*)(tab + (size_t)tg * 32
                                                + (dblk >> 1) + 2 * i);
#pragma unroll
    for (int j = 0; j < 16; j += 2) {
        float c = cs[j >> 1].x, s = cs[j >> 1].y;
        float qe = q[j], qo = q[j + 1];
        q[j] = qe * c - qo * s; q[j + 1] = qe * s + qo * c;
        float ke = k[j], ko = k[j + 1];
        k[j] = ke * c - ko * s; k[j + 1] = ke * s + ko * c;
    }
    uint32_t ph[8], pl[8];
#pragma unroll
    for (int j = 0; j < 8; ++j) {
        float f0 = q[2 * j] * 0.125f, f1 = q[2 * j + 1] * 0.125f;
        ph[j] = (uint32_t)f2bf(f0) | ((uint32_t)f2bf(f1) << 16);
    }
    *(uint4*)(Qh + dst) = *(uint4*)&ph[0]; *(uint4*)(Qh + dst + 8) = *(uint4*)&ph[4];
#pragma unroll
    for (int j = 0; j < 8; ++j) {
        float f0 = k[2 * j], f1 = k[2 * j + 1];
        unsigned short h0 = f2bf(f0), h1 = f2bf(f1);
        ph[j] = (uint32_t)h0 | ((uint32_t)h1 << 16);
        pl[j] = (uint32_t)f2bf(f0 - bf2f(h0)) | ((uint32_t)f2bf(f1 - bf2f(h1)) << 16);
    }
    *(uint4*)(Kh + dst) = *(uint4*)&ph[0]; *(uint4*)(Kh + dst + 8) = *(uint4*)&ph[4];
    *(uint4*)(Kl + dst) = *(uint4*)&pl[0]; *(uint4*)(Kl + dst + 8) = *(uint4*)&pl[4];

#pragma unroll
    for (int j = 0; j < 16; ++j) vt[r][dblk + j] = v[j];
    __syncthreads();
    const int d2 = tid >> 2;
    const int tb = (tid & 3) * 16;
#pragma unroll
    for (int j = 0; j < 8; ++j) {
        float f0 = vt[tb + 2 * j][d2], f1 = vt[tb + 2 * j + 1][d2];
        ph[j] = (uint32_t)f2bf(f0) | ((uint32_t)f2bf(f1) << 16);
    }
    const size_t vdst = ((size_t)bh * 64 + d2) * SEQ + tt * 64 + tb;
    *(uint4*)(Vh + vdst) = *(uint4*)&ph[0]; *(uint4*)(Vh + vdst + 8) = *(uint4*)&ph[4];
}

// ---------------------------------------------------------------------------
// MFMA flash attention (R12 structure, unchanged): single-buffer 32KB LDS,
// 1024 blocks, 4 blocks/CU; cvt_pk P pack; full-mask fast path; mask bitmap
// in lane registers; bijective XCD swizzle (4 bh per XCD).
// ---------------------------------------------------------------------------
__global__ __launch_bounds__(256, 4) void flash_mfma(
    const unsigned short* __restrict__ Qh,
    const unsigned short* __restrict__ Kh, const unsigned short* __restrict__ Kl,
    const unsigned short* __restrict__ Vh,
    const unsigned long long* __restrict__ mbits,
    unsigned short* __restrict__ attnx)
{
    __shared__ __align__(16) unsigned short sKh[4096];
    __shared__ __align__(16) unsigned short sKl[4096];
    __shared__ __align__(16) unsigned short sVh[4096];
    __shared__ __align__(16) unsigned short sP[4096];

    const int tid = threadIdx.x;
    const int lane = tid & 63, w = tid >> 6;
    const int l15 = lane & 15, quad = lane >> 4;
    const int lin0 = blockIdx.x;
    const int xcd = lin0 & 7, idx = lin0 >> 3;     // 1024 = 8 XCD * 128
    const int bh = xcd * 4 + (idx & 3);            // 4 bh per XCD (L2-resident)
    const int qt = 31 - (idx >> 2);                // heavy q-tiles start first
    const int b = bh >> 4, h = bh & 15;
    const int sw = (quad ^ ((l15 >> 1) & 3)) * 8;
    const int ch = (lane & 3) ^ ((lane >> 3) & 3);
    unsigned short* pbase = sP + w * 1024;

    short8 ones;
#pragma unroll
    for (int j = 0; j < 8; ++j) ones[j] = (short)0x3F80;  // bf16 1.0

    const size_t qb = ((size_t)bh * SEQ + qt * 64 + w * 16 + l15) * 64 + quad * 8;
    const short8 qh0 = *(const short8*)(Qh + qb);
    const short8 qh1 = *(const short8*)(Qh + qb + 32);

    // lane l (<32) holds the mask word of k-tile l for this batch
    unsigned int mlo = 0xffffffffu, mhi = 0xffffffffu;
    if (lane < 32) {
        unsigned long long mw = mbits[b * 32 + lane];
        mlo = (unsigned int)mw;
        mhi = (unsigned int)(mw >> 32);
    }
    const bool fullmask =
        (__ballot((mlo & mhi) == 0xffffffffu) == ~0ull);

    const size_t kRow0 = ((size_t)bh * SEQ + w * 16 + (lane >> 2)) * 64 + ch * 8;
    const size_t vRow  = ((size_t)bh * 64 + w * 16 + (lane >> 2)) * SEQ + ch * 8;

    floatx4 O[4];
    floatx4 lAcc = (floatx4)0.f;
#pragma unroll
    for (int nf = 0; nf < 4; ++nf) O[nf] = (floatx4)0.f;

    const int mg = qt * 64 + w * 16 + l15;

    for (int kt = 0; kt <= qt; ++kt) {
        __syncthreads();
        {
            const size_t kg = kRow0 + (size_t)kt * 64 * 64;
            const size_t vg = vRow + kt * 64;
            GLD_LDS16(Kh + kg,      sKh + w * 512);
            GLD_LDS16(Kh + kg + 32, sKh + 2048 + w * 512);
            GLD_LDS16(Kl + kg,      sKl + w * 512);
            GLD_LDS16(Kl + kg + 32, sKl + 2048 + w * 512);
            GLD_LDS16(Vh + vg,      sVh + w * 512);
            GLD_LDS16(Vh + vg + 32, sVh + 2048 + w * 512);
        }
        __syncthreads();

        const bool diag = (kt == qt);
        unsigned int wlo = 0xffffffffu, whi = 0xffffffffu;
        if (!fullmask) {
            wlo = (unsigned int)__shfl((int)mlo, kt);
            whi = (unsigned int)__shfl((int)mhi, kt);
        }

        // ---- S^T = K Q^T (x2), exp, pack, stage P (wave-private) ----
#pragma unroll
        for (int nf = 0; nf < 4; ++nf) {
            const int base = (nf * 16 + l15) * 32 + sw;
            const short8 kh0 = *(const short8*)&sKh[base];
            const short8 kh1 = *(const short8*)&sKh[2048 + base];
            const short8 kl0 = *(const short8*)&sKl[base];
            const short8 kl1 = *(const short8*)&sKl[2048 + base];
            floatx4 s = (floatx4)0.f;
            s = BMFMA(kh0, qh0, s);
            s = BMFMA(kh1, qh1, s);
            s = BMFMA(kl0, qh0, s);
            s = BMFMA(kl1, qh1, s);

            float pv[4];
            if (fullmask && !diag) {               // wave-uniform fast path
#pragma unroll
                for (int r = 0; r < 4; ++r)
                    pv[r] = __expf(s[r] - 16.0f);
            } else {
                const int tb = kt * 64 + nf * 16 + quad * 4;
                const unsigned int msel = (nf & 2) ? whi : wlo;
                const int p4 = (nf & 1) * 16 + quad * 4;
#pragma unroll
                for (int r = 0; r < 4; ++r) {
                    bool ok = ((msel >> (p4 + r)) & 1u) != 0u;
                    if (diag) ok = ok && (tb + r <= mg);
                    pv[r] = ok ? __expf(s[r] - 16.0f) : 0.0f;
                }
            }
            uint32_t w0, w1;
            asm("v_cvt_pk_bf16_f32 %0, %1, %2" : "=v"(w0) : "v"(pv[0]), "v"(pv[1]));
            asm("v_cvt_pk_bf16_f32 %0, %1, %2" : "=v"(w1) : "v"(pv[2]), "v"(pv[3]));
            const int pos = (((nf & 1) * 2 + (quad >> 1)) ^ ((l15 >> 1) & 3));
            *(uint2*)(pbase + (nf >> 1) * 512 + l15 * 32 + pos * 8
                      + (quad & 1) * 4) = make_uint2(w0, w1);
        }

        const short8 pf0 = *(const short8*)(pbase + l15 * 32 + sw);
        const short8 pf1 = *(const short8*)(pbase + 512 + l15 * 32 + sw);

        // ---- l += P @ ones ; O += P @ Vh ----
        lAcc = BMFMA(pf0, ones, lAcc);
        lAcc = BMFMA(pf1, ones, lAcc);
#pragma unroll
        for (int nf = 0; nf < 4; ++nf) {
            const int vb = (nf * 16 + l15) * 32 + sw;
            floatx4 o = O[nf];
            o = BMFMA(pf0, *(const short8*)&sVh[vb], o);
            o = BMFMA(pf1, *(const short8*)&sVh[2048 + vb], o);
            O[nf] = o;
        }
    }

    // ---- finalize: divide by l, store plain bf16 ----
    float rl[4];
#pragma unroll
    for (int r = 0; r < 4; ++r) rl[r] = 1.0f / lAcc[r];
#pragma unroll
    for (int nf = 0; nf < 4; ++nf)
#pragma unroll
        for (int r = 0; r < 4; ++r) {
            const int tok = b * SEQ + qt * 64 + w * 16 + quad * 4 + r;
            const int col = h * 64 + nf * 16 + l15;
            attnx[(size_t)tok * 1024 + col] = f2bf(O[nf][r] * rl[r]);
        }
}

// ---------------------------------------------------------------------------
extern "C" void kernel_launch(void* const* d_in, const int* in_sizes, int n_in,
                              void* d_out, int out_size, void* d_ws, size_t ws_size,
                              hipStream_t stream)
{
    const float* x    = (const float*)d_in[0];
    const int*   am   = (const int*)d_in[1];
    const float* Wqkv = (const float*)d_in[2];
    const float* bqkv = (const float*)d_in[3];
    const float* Wout = (const float*)d_in[4];
    const float* bout = (const float*)d_in[5];
    float* out = (float*)d_out;

    // ws layout (113.2 MB total, unchanged footprint):
    //   Bt fp16 [3072][1024] 6.29MB | Bt2 bf16 [1024][1024] 2.10MB |
    //   tab 0.52MB | mbits 512B | pad | qkv fp32 50.33MB @12582912
    //   (reused as attnx bf16 after prep) | Qh Kh Kl Vh 8.39MB each |
    //   Axh fp16 hi|lo 16.78MB @96468992 (dead after projection GEMM)
    char* ws = (char*)d_ws;
    unsigned short* Bt  = (unsigned short*)ws;
    unsigned short* Bt2 = (unsigned short*)(ws + 6291456);
    float2* tab = (float2*)(ws + 8388608);
    unsigned long long* mbits = (unsigned long long*)(ws + 8912896);
    float* qkv = (float*)(ws + 12582912);
    unsigned short* attnx = (unsigned short*)qkv;        // alias: qkv dead after prep
    unsigned short* Qh = (unsigned short*)(ws + 62914560);
    unsigned short* Kh = (unsigned short*)(ws + 71303168);
    unsigned short* Kl = (unsigned short*)(ws + 79691776);
    unsigned short* Vh = (unsigned short*)(ws + 88080384);
    unsigned short* Axh = (unsigned short*)(ws + 96468992);

    // 0) x -> Axh, W_qkv -> Bt, W_out -> Bt2, mask -> mbits, RoPE table
    split_inputs<<<8209, 256, 0, stream>>>(x, Wqkv, Wout, am,
                                           Axh, Bt, Bt2, mbits, tab);

    // 1) qkv = x @ Wqkv + b, merged fp16 kernel (x2 on Q,K cols; x1 on V)
    gemm_qkv_f16<<<768, 256, 0, stream>>>(Axh, Bt, bqkv, qkv);

    // 2) RoPE (table) + scale + split (Q hi, K hi+lo, V hi transposed)
    prep_qkv<<<1024, 256, 0, stream>>>(qkv, tab, Qh, Kh, Kl, Vh);

    // 3) MFMA flash attention -> attnx
    flash_mfma<<<1024, 256, 0, stream>>>(Qh, Kh, Kl, Vh, mbits, attnx);

    // 4) out = attn @ W_out + b  (single bf16)
    gemm_mfma_s<2, 2, 4, 4><<<256, 256, 0, stream>>>(
        attnx, 1024, Bt2, 1024, bout, out, 1024, 8);
}

// Round 4
// 193.392 us; speedup vs baseline: 1.3216x; 1.0886x over previous
//
#include <hip/hip_runtime.h>
#include <math.h>
#include <stdint.h>

#define D_MODEL 1024
#define N_HEADS 16
#define HEAD_DIM 64
#define BATCH 2
#define SEQ 2048
#define TOKENS (BATCH * SEQ)   // 4096

typedef __attribute__((ext_vector_type(8))) short short8;      // 8 bf16
typedef __attribute__((ext_vector_type(8))) _Float16 half8;    // 8 fp16
typedef __attribute__((ext_vector_type(4))) float floatx4;     // MFMA C/D frag

#define BMFMA(a, b, c) __builtin_amdgcn_mfma_f32_16x16x32_bf16(a, b, c, 0, 0, 0)
#define HMFMA(a, b, c) __builtin_amdgcn_mfma_f32_16x16x32_f16(a, b, c, 0, 0, 0)

__device__ __forceinline__ unsigned short f2bf(float f) {
    uint32_t u = __float_as_uint(f);
    u += 0x7fffu + ((u >> 16) & 1u);
    return (unsigned short)(u >> 16);
}
__device__ __forceinline__ float bf2f(unsigned short h) {
    return __uint_as_float(((uint32_t)h) << 16);
}
__device__ __forceinline__ unsigned short f2h(float f) {
    union { _Float16 h; unsigned short u; } cv;
    cv.h = (_Float16)f;            // RNE
    return cv.u;
}
__device__ __forceinline__ float h2f(unsigned short u) {
    union { unsigned short u; _Float16 h; } cv;
    cv.u = u;
    return (float)cv.h;
}
// unpack 16 consecutive fp16 -> float[16]
__device__ __forceinline__ void ld16h(const unsigned short* p, float* f) {
    uint4 u0 = *(const uint4*)p;
    uint4 u1 = *(const uint4*)(p + 8);
    const uint32_t* a = (const uint32_t*)&u0;
    const uint32_t* b = (const uint32_t*)&u1;
#pragma unroll
    for (int j = 0; j < 4; ++j) {
        f[2 * j]     = h2f((unsigned short)(a[j] & 0xffffu));
        f[2 * j + 1] = h2f((unsigned short)(a[j] >> 16));
        f[8 + 2 * j]     = h2f((unsigned short)(b[j] & 0xffffu));
        f[8 + 2 * j + 1] = h2f((unsigned short)(b[j] >> 16));
    }
}

// async global -> LDS, 16B per lane; LDS dest = wave-uniform base + lane*16
#define GLD_LDS16(gp, lp) __builtin_amdgcn_global_load_lds(                 \
    (const __attribute__((address_space(1))) void*)(gp),                    \
    (__attribute__((address_space(3))) void*)(lp), 16, 0, 0)

// ---------------------------------------------------------------------------
// Merged input prep:
//   blocks [0,2048)      : x -> Axh (single fp16 [4096][1024])
//   blocks [2048,5120)   : W_qkv -> Bt (transpose, single fp16 [3072n][1024k])
//   blocks [5120,6144)   : W_out -> Bt2 (transpose, single fp16 [1024n][1024k])
//   block  6144          : attention_mask -> 64-bit per-k-tile bitmask
//   blocks [6145,6161)   : RoPE cos/sin table [t][32] float2
// ---------------------------------------------------------------------------
__global__ __launch_bounds__(256) void split_inputs(
    const float* __restrict__ X, const float* __restrict__ Wqkv,
    const float* __restrict__ Wout, const int* __restrict__ am,
    unsigned short* __restrict__ Axh, unsigned short* __restrict__ Bt,
    unsigned short* __restrict__ Bt2, unsigned long long* __restrict__ mbits,
    float2* __restrict__ tab)
{
    __shared__ float t[32][33];
    const int tid = threadIdx.x;
    const int bid = blockIdx.x;
    if (bid < 2048) {
        const int idx = bid * 2048 + tid * 8;
        const int row = idx >> 10;
        const int c = idx & 1023;
        float4 v0 = *(const float4*)(X + (size_t)row * 1024 + c);
        float4 v1 = *(const float4*)(X + (size_t)row * 1024 + c + 4);
        float f[8] = {v0.x, v0.y, v0.z, v0.w, v1.x, v1.y, v1.z, v1.w};
        uint32_t p[4];
#pragma unroll
        for (int j = 0; j < 4; ++j)
            p[j] = (uint32_t)f2h(f[2 * j]) | ((uint32_t)f2h(f[2 * j + 1]) << 16);
        *(uint4*)(Axh + (size_t)row * 1024 + c) = *(uint4*)p;
    } else if (bid < 5120) {
        const int id = bid - 2048;                 // 0..3071
        const int n0 = (id % 96) * 32, k0 = (id / 96) * 32;
        const int c = tid & 31, r = tid >> 5;
#pragma unroll
        for (int i = 0; i < 4; ++i)
            t[r + 8 * i][c] = Wqkv[(size_t)(k0 + r + 8 * i) * 3072 + n0 + c];
        __syncthreads();
#pragma unroll
        for (int i = 0; i < 4; ++i) {
            int dn = r + 8 * i;
            Bt[(size_t)(n0 + dn) * 1024 + k0 + c] = f2h(t[c][dn]);
        }
    } else if (bid < 6144) {
        const int id = bid - 5120;                 // 0..1023: W_out 32x32 tiles
        const int n0 = (id & 31) * 32, k0 = (id >> 5) * 32;
        const int c = tid & 31, r = tid >> 5;
#pragma unroll
        for (int i = 0; i < 4; ++i)
            t[r + 8 * i][c] = Wout[(size_t)(k0 + r + 8 * i) * 1024 + n0 + c];
        __syncthreads();
#pragma unroll
        for (int i = 0; i < 4; ++i) {
            int dn = r + 8 * i;
            Bt2[(size_t)(n0 + dn) * 1024 + k0 + c] = f2h(t[c][dn]);
        }
    } else if (bid == 6144) {
        // mask bitmap: one uint64 per 64-token tile (B*SEQ/64 = 64 tiles)
        if (tid < 64) {
            const int* a = am + tid * 64;
            unsigned long long m = 0ull;
            for (int j = 0; j < 64; ++j)
                m |= (unsigned long long)(a[j] != 0 ? 1u : 0u) << j;
            mbits[tid] = m;
        }
    } else {
        // RoPE table: 2048 x 32 float2 (cos, sin)
        const int i = bid - 6145;                  // 0..15
#pragma unroll
        for (int e = 0; e < 16; ++e) {
            int idx = i * 4096 + e * 256 + tid;
            int tt = idx >> 5, pr = idx & 31;
            double ex = (double)(2 * pr) / 64.0;
            float inv = (float)exp2(-ex * 13.287712379549449);
            float ang = (float)tt * inv;
            float s, c;
            __sincosf(ang, &s, &c);
            tab[idx] = make_float2(c, s);
        }
    }
}

// ---------------------------------------------------------------------------
// Single-precision fp16 MFMA GEMM. BK=64, runtime A/B/C strides.
// OUT16: C is fp16 (qkv intermediate); else C fp32 (final out).
// Used for: QKV projection (768 blocks) and out-projection (256 blocks).
// ---------------------------------------------------------------------------
template<int WM, int WN, int FM, int FN, int OUT16>
__global__ __launch_bounds__(256) void gemm_mfma_h(
    const unsigned short* __restrict__ A, int lda,
    const unsigned short* __restrict__ Bt, int ldb,
    const float* __restrict__ bias, void* __restrict__ Cv, int ldc, int nTiles)
{
    constexpr int BM = WM * FM * 16;
    constexpr int BN = WN * FN * 16;
    constexpr int NA = BM / 64;
    constexpr int NB = BN / 64;

    __shared__ __align__(16) unsigned short sA0[BM * 32];
    __shared__ __align__(16) unsigned short sA1[BM * 32];
    __shared__ __align__(16) unsigned short sB0[BN * 32];
    __shared__ __align__(16) unsigned short sB1[BN * 32];

    const int tid = threadIdx.x;
    const int w = tid >> 6, lane = tid & 63;
    const int l15 = lane & 15, quad = lane >> 4;
    const int wm = w / WN, wn = w % WN;

    const int lin = blockIdx.x;
    const int msuper = lin / (8 * nTiles);
    const int rem = lin % (8 * nTiles);
    const int m0 = (msuper * 8 + (rem & 7)) * BM;
    const int n0 = (rem >> 3) * BN;

    const int ch = (lane & 3) ^ ((lane >> 3) & 3);
    const int sw = (quad ^ ((l15 >> 1) & 3)) * 8;

    const unsigned short* aG[NA];
    const unsigned short* bG[NB];
#pragma unroll
    for (int i = 0; i < NA; ++i)
        aG[i] = A + (size_t)(m0 + (w * NA + i) * 16 + (lane >> 2)) * lda + ch * 8;
#pragma unroll
    for (int i = 0; i < NB; ++i)
        bG[i] = Bt + (size_t)(n0 + (w * NB + i) * 16 + (lane >> 2)) * ldb + ch * 8;

    floatx4 acc[FM][FN];
#pragma unroll
    for (int fm = 0; fm < FM; ++fm)
#pragma unroll
        for (int fn = 0; fn < FN; ++fn) acc[fm][fn] = (floatx4)0.f;

    for (int ks = 0; ks < 16; ++ks) {
        const int ko = ks * 64;
        __syncthreads();
#pragma unroll
        for (int i = 0; i < NA; ++i) {
            GLD_LDS16(aG[i] + ko,      sA0 + (w * NA + i) * 512);
            GLD_LDS16(aG[i] + ko + 32, sA1 + (w * NA + i) * 512);
        }
#pragma unroll
        for (int i = 0; i < NB; ++i) {
            GLD_LDS16(bG[i] + ko,      sB0 + (w * NB + i) * 512);
            GLD_LDS16(bG[i] + ko + 32, sB1 + (w * NB + i) * 512);
        }
        __syncthreads();

        half8 a0[FM], a1[FM], b0[FN], b1[FN];
#pragma unroll
        for (int fm = 0; fm < FM; ++fm) {
            const int off = ((wm * FM + fm) * 16 + l15) * 32 + sw;
            a0[fm] = *(const half8*)&sA0[off];
            a1[fm] = *(const half8*)&sA1[off];
        }
#pragma unroll
        for (int fn = 0; fn < FN; ++fn) {
            const int off = ((wn * FN + fn) * 16 + l15) * 32 + sw;
            b0[fn] = *(const half8*)&sB0[off];
            b1[fn] = *(const half8*)&sB1[off];
        }
#pragma unroll
        for (int fm = 0; fm < FM; ++fm)
#pragma unroll
            for (int fn = 0; fn < FN; ++fn) {
                floatx4 a = acc[fm][fn];
                a = HMFMA(a0[fm], b0[fn], a);
                a = HMFMA(a1[fm], b1[fn], a);
                acc[fm][fn] = a;
            }
    }

#pragma unroll
    for (int fm = 0; fm < FM; ++fm)
#pragma unroll
        for (int fn = 0; fn < FN; ++fn) {
            int col = n0 + (wn * FN + fn) * 16 + l15;
            float bv = bias[col];
#pragma unroll
            for (int r = 0; r < 4; ++r) {
                int row = m0 + (wm * FM + fm) * 16 + quad * 4 + r;
                if (OUT16) {
                    ((unsigned short*)Cv)[(size_t)row * ldc + col] =
                        f2h(acc[fm][fn][r] + bv);
                } else {
                    ((float*)Cv)[(size_t)row * ldc + col] =
                        acc[fm][fn][r] + bv;
                }
            }
        }
}

// ---------------------------------------------------------------------------
// prep_qkv: RoPE (table-driven) + 1/8 q-scale. Reads fp16 qkv.
// Q fp16 / K fp16 [bh][t][64]; V bf16 [bh][d][2048] transposed.
// ---------------------------------------------------------------------------
__global__ __launch_bounds__(256) void prep_qkv(
    const unsigned short* __restrict__ qkvh, const float2* __restrict__ tab,
    unsigned short* __restrict__ Qh, unsigned short* __restrict__ Kh,
    unsigned short* __restrict__ Vh)
{
    __shared__ float vt[64][65];
    const int tid = threadIdx.x;
    const int lin = blockIdx.x;
    const int tt = lin & 31, bh = lin >> 5;
    const int b = bh >> 4, h = bh & 15;
    const int r = tid >> 2;
    const int dblk = (tid & 3) * 16;
    const int tg = tt * 64 + r;
    const size_t src = (size_t)(b * SEQ + tg) * 3072 + h * 64 + dblk;
    const size_t dst = ((size_t)bh * SEQ + tg) * 64 + dblk;

    float q[16], k[16], v[16];
    ld16h(qkvh + src, q);
    ld16h(qkvh + src + 1024, k);
    ld16h(qkvh + src + 2048, v);

    float2 cs[8];
#pragma unroll
    for (int i = 0; i < 4; ++i)
        *(float4*)&cs[2 * i] = *(const float4*)(tab + (size_t)tg * 32
                                                + (dblk >> 1) + 2 * i);
#pragma unroll
    for (int j = 0; j < 16; j += 2) {
        float c = cs[j >> 1].x, s = cs[j >> 1].y;
        float qe = q[j], qo = q[j + 1];
        q[j] = qe * c - qo * s; q[j + 1] = qe * s + qo * c;
        float ke = k[j], ko = k[j + 1];
        k[j] = ke * c - ko * s; k[j + 1] = ke * s + ko * c;
    }
    uint32_t ph[8];
#pragma unroll
    for (int j = 0; j < 8; ++j) {
        float f0 = q[2 * j] * 0.125f, f1 = q[2 * j + 1] * 0.125f;
        ph[j] = (uint32_t)f2h(f0) | ((uint32_t)f2h(f1) << 16);
    }
    *(uint4*)(Qh + dst) = *(uint4*)&ph[0]; *(uint4*)(Qh + dst + 8) = *(uint4*)&ph[4];
#pragma unroll
    for (int j = 0; j < 8; ++j)
        ph[j] = (uint32_t)f2h(k[2 * j]) | ((uint32_t)f2h(k[2 * j + 1]) << 16);
    *(uint4*)(Kh + dst) = *(uint4*)&ph[0]; *(uint4*)(Kh + dst + 8) = *(uint4*)&ph[4];

#pragma unroll
    for (int j = 0; j < 16; ++j) vt[r][dblk + j] = v[j];
    __syncthreads();
    const int d2 = tid >> 2;
    const int tb = (tid & 3) * 16;
#pragma unroll
    for (int j = 0; j < 8; ++j) {
        float f0 = vt[tb + 2 * j][d2], f1 = vt[tb + 2 * j + 1][d2];
        ph[j] = (uint32_t)f2bf(f0) | ((uint32_t)f2bf(f1) << 16);
    }
    const size_t vdst = ((size_t)bh * 64 + d2) * SEQ + tt * 64 + tb;
    *(uint4*)(Vh + vdst) = *(uint4*)&ph[0]; *(uint4*)(Vh + vdst + 8) = *(uint4*)&ph[4];
}

// ---------------------------------------------------------------------------
// MFMA flash attention, R14: S-path in single fp16 (Q fp16, K fp16, 2^-12
// mantissa replaces bf16 hi/lo -> drops the entire Kl path).
//   - 18 MFMA/iter (8 S fp16 + 2 l + 8 O bf16), 4 DMA loads/iter, LDS 24KB
//   - softmax / P(bf16) / V(bf16) path bit-identical to R12/R13
//   - balanced qt pairing in grid map: groups of 4 blocks get qt
//     {g,31-g,g,31-g} -> uniform work under either block->CU assignment
//   - XCD swizzle: 4 bh per XCD (L2-resident K/V)
// ---------------------------------------------------------------------------
__global__ __launch_bounds__(256, 4) void flash_mfma(
    const unsigned short* __restrict__ Qh, const unsigned short* __restrict__ Kh,
    const unsigned short* __restrict__ Vh,
    const unsigned long long* __restrict__ mbits,
    unsigned short* __restrict__ attnx)
{
    __shared__ __align__(16) unsigned short sK[4096];
    __shared__ __align__(16) unsigned short sV[4096];
    __shared__ __align__(16) unsigned short sP[4096];

    const int tid = threadIdx.x;
    const int lane = tid & 63, w = tid >> 6;
    const int l15 = lane & 15, quad = lane >> 4;
    const int lin0 = blockIdx.x;
    const int xcd = lin0 & 7, idx = lin0 >> 3;     // 1024 = 8 XCD * 128
    const int g = idx >> 2, j = idx & 3;
    const int bh = xcd * 4 + j;                    // 4 bh per XCD (L2-resident)
    const int qt = (j & 1) ? (31 - g) : g;         // balanced qt pairing
    const int b = bh >> 4, h = bh & 15;
    const int sw = (quad ^ ((l15 >> 1) & 3)) * 8;
    const int ch = (lane & 3) ^ ((lane >> 3) & 3);
    unsigned short* pbase = sP + w * 1024;

    short8 ones;
#pragma unroll
    for (int jj = 0; jj < 8; ++jj) ones[jj] = (short)0x3F80;  // bf16 1.0

    const size_t qb = ((size_t)bh * SEQ + qt * 64 + w * 16 + l15) * 64 + quad * 8;
    const half8 qh0 = *(const half8*)(Qh + qb);
    const half8 qh1 = *(const half8*)(Qh + qb + 32);

    // lane l (<32) holds the mask word of k-tile l for this batch
    unsigned int mlo = 0xffffffffu, mhi = 0xffffffffu;
    if (lane < 32) {
        unsigned long long mw = mbits[b * 32 + lane];
        mlo = (unsigned int)mw;
        mhi = (unsigned int)(mw >> 32);
    }
    const bool fullmask =
        (__ballot((mlo & mhi) == 0xffffffffu) == ~0ull);

    const size_t kRow0 = ((size_t)bh * SEQ + w * 16 + (lane >> 2)) * 64 + ch * 8;
    const size_t vRow  = ((size_t)bh * 64 + w * 16 + (lane >> 2)) * SEQ + ch * 8;

    floatx4 O[4];
    floatx4 lAcc = (floatx4)0.f;
#pragma unroll
    for (int nf = 0; nf < 4; ++nf) O[nf] = (floatx4)0.f;

    const int mg = qt * 64 + w * 16 + l15;

    for (int kt = 0; kt <= qt; ++kt) {
        __syncthreads();
        {
            const size_t kg = kRow0 + (size_t)kt * 64 * 64;
            const size_t vg = vRow + kt * 64;
            GLD_LDS16(Kh + kg,      sK + w * 512);
            GLD_LDS16(Kh + kg + 32, sK + 2048 + w * 512);
            GLD_LDS16(Vh + vg,      sV + w * 512);
            GLD_LDS16(Vh + vg + 32, sV + 2048 + w * 512);
        }
        __syncthreads();

        const bool diag = (kt == qt);
        unsigned int wlo = 0xffffffffu, whi = 0xffffffffu;
        if (!fullmask) {
            wlo = (unsigned int)__shfl((int)mlo, kt);
            whi = (unsigned int)__shfl((int)mhi, kt);
        }

        // ---- S^T = K Q^T (fp16), exp, pack bf16, stage P (wave-private) ----
#pragma unroll
        for (int nf = 0; nf < 4; ++nf) {
            const int base = (nf * 16 + l15) * 32 + sw;
            const half8 k0 = *(const half8*)&sK[base];
            const half8 k1 = *(const half8*)&sK[2048 + base];
            floatx4 s = (floatx4)0.f;
            s = HMFMA(k0, qh0, s);
            s = HMFMA(k1, qh1, s);

            float pv[4];
            if (fullmask && !diag) {               // wave-uniform fast path
#pragma unroll
                for (int r = 0; r < 4; ++r)
                    pv[r] = __expf(s[r] - 16.0f);
            } else {
                const int tb = kt * 64 + nf * 16 + quad * 4;
                const unsigned int msel = (nf & 2) ? whi : wlo;
                const int p4 = (nf & 1) * 16 + quad * 4;
#pragma unroll
                for (int r = 0; r < 4; ++r) {
                    bool ok = ((msel >> (p4 + r)) & 1u) != 0u;
                    if (diag) ok = ok && (tb + r <= mg);
                    pv[r] = ok ? __expf(s[r] - 16.0f) : 0.0f;
                }
            }
            uint32_t w0, w1;
            asm("v_cvt_pk_bf16_f32 %0, %1, %2" : "=v"(w0) : "v"(pv[0]), "v"(pv[1]));
            asm("v_cvt_pk_bf16_f32 %0, %1, %2" : "=v"(w1) : "v"(pv[2]), "v"(pv[3]));
            const int pos = (((nf & 1) * 2 + (quad >> 1)) ^ ((l15 >> 1) & 3));
            *(uint2*)(pbase + (nf >> 1) * 512 + l15 * 32 + pos * 8
                      + (quad & 1) * 4) = make_uint2(w0, w1);
        }

        const short8 pf0 = *(const short8*)(pbase + l15 * 32 + sw);
        const short8 pf1 = *(const short8*)(pbase + 512 + l15 * 32 + sw);

        // ---- l += P @ ones ; O += P @ V  (bf16, unchanged) ----
        lAcc = BMFMA(pf0, ones, lAcc);
        lAcc = BMFMA(pf1, ones, lAcc);
#pragma unroll
        for (int nf = 0; nf < 4; ++nf) {
            const int vb = (nf * 16 + l15) * 32 + sw;
            floatx4 o = O[nf];
            o = BMFMA(pf0, *(const short8*)&sV[vb], o);
            o = BMFMA(pf1, *(const short8*)&sV[2048 + vb], o);
            O[nf] = o;
        }
    }

    // ---- finalize: divide by l, store fp16 ----
    float rl[4];
#pragma unroll
    for (int r = 0; r < 4; ++r) rl[r] = 1.0f / lAcc[r];
#pragma unroll
    for (int nf = 0; nf < 4; ++nf)
#pragma unroll
        for (int r = 0; r < 4; ++r) {
            const int tok = b * SEQ + qt * 64 + w * 16 + quad * 4 + r;
            const int col = h * 64 + nf * 16 + l15;
            attnx[(size_t)tok * 1024 + col] = f2h(O[nf][r] * rl[r]);
        }
}

// ---------------------------------------------------------------------------
extern "C" void kernel_launch(void* const* d_in, const int* in_sizes, int n_in,
                              void* d_out, int out_size, void* d_ws, size_t ws_size,
                              hipStream_t stream)
{
    const float* x    = (const float*)d_in[0];
    const int*   am   = (const int*)d_in[1];
    const float* Wqkv = (const float*)d_in[2];
    const float* bqkv = (const float*)d_in[3];
    const float* Wout = (const float*)d_in[4];
    const float* bout = (const float*)d_in[5];
    float* out = (float*)d_out;

    // ws layout (96.5 MB):
    //   Bt fp16 [3072][1024] 6.29MB @0 | Bt2 fp16 [1024][1024] 2.10MB |
    //   tab 0.52MB | mbits 512B | qkvh fp16 [4096][3072] 25.2MB @12582912
    //   (reused as attnx fp16 after prep) | Qh Kh fp16, Vh bf16 8.39MB each |
    //   Axh fp16 [4096][1024] 8.39MB @88080384 (dead after projection GEMM)
    char* ws = (char*)d_ws;
    unsigned short* Bt  = (unsigned short*)ws;
    unsigned short* Bt2 = (unsigned short*)(ws + 6291456);
    float2* tab = (float2*)(ws + 8388608);
    unsigned long long* mbits = (unsigned long long*)(ws + 8912896);
    unsigned short* qkvh = (unsigned short*)(ws + 12582912);
    unsigned short* attnx = qkvh;                        // alias: dead after prep
    unsigned short* Qh = (unsigned short*)(ws + 62914560);
    unsigned short* Kh = (unsigned short*)(ws + 71303168);
    unsigned short* Vh = (unsigned short*)(ws + 79691776);
    unsigned short* Axh = (unsigned short*)(ws + 88080384);

    // 0) x -> Axh, W_qkv -> Bt, W_out -> Bt2, mask -> mbits, RoPE table
    split_inputs<<<6161, 256, 0, stream>>>(x, Wqkv, Wout, am,
                                           Axh, Bt, Bt2, mbits, tab);

    // 1) qkv = x @ Wqkv + b, single fp16, fp16 output
    gemm_mfma_h<2, 2, 4, 4, 1><<<768, 256, 0, stream>>>(
        Axh, 1024, Bt, 1024, bqkv, qkvh, 3072, 24);

    // 2) RoPE (table) + scale: Q fp16, K fp16, V bf16 transposed
    prep_qkv<<<1024, 256, 0, stream>>>(qkvh, tab, Qh, Kh, Vh);

    // 3) MFMA flash attention -> attnx (fp16)
    flash_mfma<<<1024, 256, 0, stream>>>(Qh, Kh, Vh, mbits, attnx);

    // 4) out = attn @ W_out + b  (single fp16, fp32 output)
    gemm_mfma_h<2, 2, 4, 4, 0><<<256, 256, 0, stream>>>(
        attnx, 1024, Bt2, 1024, bout, out, 1024, 8);
}